// Round 10
// baseline (1005.384 us; speedup 1.0000x reference)
//
#include <hip/hip_runtime.h>

#define S_LEN 2048
#define NHQ 8
#define NKV 2
#define HD 256

typedef __attribute__((ext_vector_type(8))) short bf16x8;
typedef __attribute__((ext_vector_type(4))) short bf16x4;
typedef __attribute__((ext_vector_type(4))) float f32x4;
typedef __attribute__((ext_vector_type(16))) float f32x16;
typedef __attribute__((ext_vector_type(4))) unsigned u32x4;

__device__ __forceinline__ short f2bf(float f) {
    unsigned u = __builtin_bit_cast(unsigned, f);
    u += 0x7FFFu + ((u >> 16) & 1u);
    return (short)(u >> 16);
}
__device__ __forceinline__ float bf2f(short s) {
    unsigned u = ((unsigned)(unsigned short)s) << 16;
    return __builtin_bit_cast(float, u);
}
__device__ __forceinline__ unsigned cvtpk(float a, float b) {
    unsigned r;
    asm("v_cvt_pk_bf16_f32 %0, %1, %2" : "=v"(r) : "v"(a), "v"(b));
    return r;
}
__device__ __forceinline__ void gload16(const short* g, short* l) {
    __builtin_amdgcn_global_load_lds((const __attribute__((address_space(1))) unsigned*)g,
                                     (__attribute__((address_space(3))) unsigned*)l, 16, 0, 0);
}
__device__ __forceinline__ float bperm(int srclane, float v) {
    return __builtin_bit_cast(float,
        __builtin_amdgcn_ds_bpermute(srclane * 4, __builtin_bit_cast(int, v)));
}

// ---------------- fp32 -> bf16 convert ----------------
__global__ __launch_bounds__(256) void cvt_kernel(const float* __restrict__ in,
                                                  short* __restrict__ out, int n) {
    int i = (blockIdx.x * 256 + threadIdx.x) * 4;
    if (i + 3 < n) {
        float4 f = *(const float4*)(in + i);
        bf16x4 o;
        o[0] = f2bf(f.x); o[1] = f2bf(f.y); o[2] = f2bf(f.z); o[3] = f2bf(f.w);
        *(bf16x4*)(out + i) = o;
    }
}

// ---------------- fp32 W[K][N] -> bf16 Wt[N][K] (convert + transpose) -------
__global__ __launch_bounds__(256) void wt_kernel(const float* __restrict__ in,
                                                 short* __restrict__ out,
                                                 int K, int N) {
    __shared__ short tile[64][72];
    int n0 = blockIdx.x * 64, k0 = blockIdx.y * 64;
    int t = threadIdx.x;
    #pragma unroll
    for (int i = 0; i < 16; i++) {
        int flat = i * 256 + t; int r = flat >> 6, c = flat & 63;
        tile[r][c] = f2bf(in[(long)(k0 + r) * N + n0 + c]);
    }
    __syncthreads();
    #pragma unroll
    for (int i = 0; i < 16; i++) {
        int flat = i * 256 + t; int r = flat >> 6, c = flat & 63;
        out[(long)(n0 + r) * K + k0 + c] = tile[c][r];
    }
}

// ---------------- m97-style GEMM: C[M][N] = A[M][K] @ Bt[N][K]^T ------------
template<int BN, int WRITE_BF16>
__global__ __launch_bounds__(256) void gemm_bt(const short* __restrict__ A,
                                               const short* __restrict__ Bt,
                                               void* __restrict__ Cv,
                                               int M, int N, int K) {
    constexpr int NI = BN / 32;          // B-frags per wave
    __shared__ short As[128 * 32];
    __shared__ short Bs[BN * 32];
    const int t = threadIdx.x;
    const int lane = t & 63, w = t >> 6;
    const int lr = lane & 15, lg = lane >> 4;
    const int m0 = blockIdx.y * 128, n0 = blockIdx.x * BN;
    const int wm = (w >> 1) * 64, wn = (w & 1) * (BN / 2);

    f32x4 acc[4][NI];
    #pragma unroll
    for (int i = 0; i < 4; i++)
        #pragma unroll
        for (int j = 0; j < NI; j++) acc[i][j] = (f32x4){0.f, 0.f, 0.f, 0.f};

    for (int k0 = 0; k0 < K; k0 += 32) {
        __syncthreads();
        #pragma unroll
        for (int r = 0; r < 2; r++) {            // A tile: 128x32 = 8 KB
            int sbase = r * 2048 + w * 512;
            int srow = (sbase + lane * 8) >> 5, scol = (sbase + lane * 8) & 31;
            gload16(A + (long)(m0 + srow) * K + k0 + scol, &As[sbase]);
        }
        #pragma unroll
        for (int r = 0; r < BN / 64; r++) {      // B tile: BNx32
            int sbase = r * 2048 + w * 512;
            int srow = (sbase + lane * 8) >> 5, scol = (sbase + lane * 8) & 31;
            gload16(Bt + (long)(n0 + srow) * K + k0 + scol, &Bs[sbase]);
        }
        __syncthreads();
        bf16x8 af[4], bfr[NI];
        #pragma unroll
        for (int mi = 0; mi < 4; mi++)
            af[mi] = *(const bf16x8*)&As[(wm + mi * 16 + lr) * 32 + lg * 8];
        #pragma unroll
        for (int ni = 0; ni < NI; ni++)
            bfr[ni] = *(const bf16x8*)&Bs[(wn + ni * 16 + lr) * 32 + lg * 8];
        #pragma unroll
        for (int mi = 0; mi < 4; mi++)
            #pragma unroll
            for (int ni = 0; ni < NI; ni++)
                acc[mi][ni] = __builtin_amdgcn_mfma_f32_16x16x32_bf16(af[mi], bfr[ni], acc[mi][ni], 0, 0, 0);
    }
    #pragma unroll
    for (int mi = 0; mi < 4; mi++)
    #pragma unroll
    for (int ni = 0; ni < NI; ni++)
    #pragma unroll
    for (int r = 0; r < 4; r++) {
        long row = m0 + wm + mi * 16 + lg * 4 + r;
        long col = n0 + wn + ni * 16 + lr;
        float v = acc[mi][ni][r];
        if (WRITE_BF16) ((short*)Cv)[row * N + col] = f2bf(v);
        else            ((float*)Cv)[row * N + col] = v;
    }
}

// ---------------- RMSNorm + partial RoPE (K path) ---------------------------
__global__ __launch_bounds__(256) void norm_rope_kernel(
    const short* __restrict__ in, short* __restrict__ out,
    const float* __restrict__ w, const float* __restrict__ cosb,
    const float* __restrict__ sinb, int H, long ldin, long cofs,
    long ob, long oh, long os, float scale) {
    int vec = blockIdx.x * 4 + (threadIdx.x >> 6);
    int lane = threadIdx.x & 63;
    int token = vec / H, head = vec % H;
    int b = token / S_LEN, s = token % S_LEN;

    bf16x4 xv = *(const bf16x4*)(in + (long)token * ldin + cofs + head * 256 + lane * 4);
    float x0 = bf2f(xv[0]), x1 = bf2f(xv[1]), x2 = bf2f(xv[2]), x3 = bf2f(xv[3]);
    float ss = x0 * x0 + x1 * x1 + x2 * x2 + x3 * x3;
    #pragma unroll
    for (int m = 1; m < 64; m <<= 1) ss += __shfl_xor(ss, m);
    float inv = rsqrtf(ss * (1.f / 256.f) + 1e-6f);

    float4 wv = *(const float4*)(w + lane * 4);
    float y0 = x0 * inv * (1.f + wv.x);
    float y1 = x1 * inv * (1.f + wv.y);
    float y2 = x2 * inv * (1.f + wv.z);
    float y3 = x3 * inv * (1.f + wv.w);

    if (lane < 16) {
        float2 c = *(const float2*)&cosb[s * 32 + lane * 2];
        float2 sn = *(const float2*)&sinb[s * 32 + lane * 2];
        float a0 = y0 * c.x - y1 * sn.x, b0 = y0 * sn.x + y1 * c.x;
        float a1 = y2 * c.y - y3 * sn.y, b1 = y2 * sn.y + y3 * c.y;
        y0 = a0; y1 = b0; y2 = a1; y3 = b1;
    }
    y0 *= scale; y1 *= scale; y2 *= scale; y3 *= scale;
    long oidx = (long)b * ob + (long)head * oh + (long)s * os + lane * 4;
    bf16x4 o; o[0] = f2bf(y0); o[1] = f2bf(y1); o[2] = f2bf(y2); o[3] = f2bf(y3);
    *(bf16x4*)(out + oidx) = o;
}

// ---------------- V transpose: C[token][2560+kv*256+d] -> vr[b][kv][d][s] ---
__global__ __launch_bounds__(256) void transpose_v_kernel(const short* __restrict__ C,
                                                          short* __restrict__ vr) {
    __shared__ short tile[64][65];
    int s0 = blockIdx.x * 64, d0 = blockIdx.y * 64;
    int bkv = blockIdx.z; int b = bkv >> 1, kv = bkv & 1;
    int t = threadIdx.x;
    #pragma unroll
    for (int i = 0; i < 16; i++) {
        int flat = i * 256 + t; int si = flat >> 6, di = flat & 63;
        tile[si][di] = C[(long)(b * S_LEN + s0 + si) * 3072 + 2560 + kv * 256 + d0 + di];
    }
    __syncthreads();
    #pragma unroll
    for (int i = 0; i < 16; i++) {
        int flat = i * 256 + t; int di = flat >> 6, si = flat & 63;
        vr[(long)(bkv * 256 + d0 + di) * S_LEN + s0 + si] = tile[si][di];
    }
}

// ---------------- flash attention: 8 waves, 1 block/CU, 34 uniform phases ---
// Block = chunk pair (15-c, c) of 128 q-rows each, processed sequentially.
// Waves: 4 q-groups x 2 key parities. Phase = 64 keys, true double buffer,
// counted vmcnt(8) -> loads span 2 phases. Q norm+rope fused (per chunk).
__global__ __launch_bounds__(512, 1) void flash_kernel(const short* __restrict__ Cq,
                                                       const short* __restrict__ Kt,
                                                       const short* __restrict__ Vt,
                                                       short* __restrict__ O,
                                                       const float* __restrict__ qnw,
                                                       const float* __restrict__ cosb,
                                                       const float* __restrict__ sinb) {
    // buf i at i*65536: K 64x512B (swz (key&7)<<4) + V 256x128B (swz (d&7)<<4)
    // scratch at 131072 (16 KB acc rounds), ml at 147456. Total 147968.
    __shared__ __align__(16) char smem[147968];

    int idx = blockIdx.x;
    int xcd = idx & 7, r5 = idx >> 3;
    int bh = xcd * 2 + (r5 & 1);             // per-XCD KV slice = 2 MB (L2-fit)
    int c  = r5 >> 1;                        // 0..15
    int jA = 15 - c, jB = c;                 // chunk pair: 34 phases total, uniform
    int h = bh & 7, b = bh >> 3;
    int kv = h >> 2;
    int t = threadIdx.x, lane = t & 63, w = t >> 6;
    int g = w >> 1, p = w & 1;               // q-group (32 rows), key parity
    int ln = lane & 31, hi = lane >> 5;

    const short* Kb = Kt + (long)(b * NKV + kv) * S_LEN * HD;
    const short* Vb = Vt + (long)(b * NKV + kv) * HD * S_LEN;

    const int nphA = 2 * (jA + 1), nphB = 2 * (jB + 1);
    const int nt = nphA + nphB;              // == 34

    // stage 64-key tile pair at absolute key base kbase into buf (8 loads/thr)
    auto stage = [&](int buf, int kbase) {
        short* Kt0 = (short*)(smem + buf * 65536);
        short* Vt0 = (short*)(smem + buf * 65536 + 32768);
        #pragma unroll
        for (int cc = 0; cc < 4; cc++) {
            int o = cc * 8192 + w * 1024 + lane * 16;
            int key = o >> 9, db = o & 511;
            gload16(Kb + (long)(kbase + key) * HD + ((db ^ ((key & 7) << 4)) >> 1),
                    Kt0 + (cc * 8192 + w * 1024) / 2);
            int d = o >> 7, kb = o & 127;
            gload16(Vb + (long)d * S_LEN + kbase + ((kb ^ ((d & 7) << 4)) >> 1),
                    Vt0 + (cc * 8192 + w * 1024) / 2);
        }
    };

    bf16x8 qf[16];
    f32x16 acc[8];
    float m, l;

    auto qnorm = [&](int j) {
        int qgl = j * 128 + g * 32 + ln;
        const short* qrow = Cq + (long)(b * S_LEN + qgl) * 3072 + h * 256 + hi * 8;
        #pragma unroll
        for (int dc = 0; dc < 16; dc++) qf[dc] = *(const bf16x8*)&qrow[dc * 16];
        float ss = 0.f;
        #pragma unroll
        for (int dc = 0; dc < 16; dc++)
            #pragma unroll
            for (int e = 0; e < 8; e++) { float v = bf2f(qf[dc][e]); ss += v * v; }
        ss += __shfl_xor(ss, 32);
        float inv = rsqrtf(ss * (1.f / 256.f) + 1e-6f);
        #pragma unroll
        for (int dc = 0; dc < 16; dc++) {
            float y[8];
            float4 w0 = *(const float4*)&qnw[dc * 16 + hi * 8];
            float4 w1 = *(const float4*)&qnw[dc * 16 + hi * 8 + 4];
            y[0] = bf2f(qf[dc][0]) * inv * (1.f + w0.x);
            y[1] = bf2f(qf[dc][1]) * inv * (1.f + w0.y);
            y[2] = bf2f(qf[dc][2]) * inv * (1.f + w0.z);
            y[3] = bf2f(qf[dc][3]) * inv * (1.f + w0.w);
            y[4] = bf2f(qf[dc][4]) * inv * (1.f + w1.x);
            y[5] = bf2f(qf[dc][5]) * inv * (1.f + w1.y);
            y[6] = bf2f(qf[dc][6]) * inv * (1.f + w1.z);
            y[7] = bf2f(qf[dc][7]) * inv * (1.f + w1.w);
            if (dc < 4) {   // d < 64: rope pairs (2i,2i+1)
                float4 c4 = *(const float4*)&cosb[qgl * 32 + dc * 8 + hi * 4];
                float4 s4 = *(const float4*)&sinb[qgl * 32 + dc * 8 + hi * 4];
                float a, bb;
                a = y[0]; bb = y[1]; y[0] = a * c4.x - bb * s4.x; y[1] = a * s4.x + bb * c4.x;
                a = y[2]; bb = y[3]; y[2] = a * c4.y - bb * s4.y; y[3] = a * s4.y + bb * c4.y;
                a = y[4]; bb = y[5]; y[4] = a * c4.z - bb * s4.z; y[5] = a * s4.z + bb * c4.z;
                a = y[6]; bb = y[7]; y[6] = a * c4.w - bb * s4.w; y[7] = a * s4.w + bb * c4.w;
            }
            bf16x8 o;
            #pragma unroll
            for (int e = 0; e < 8; e++) o[e] = f2bf(y[e] * 0.0625f);
            qf[dc] = o;
        }
    };

    auto compute = [&](int buf, int kbase, int q0) {
        const char* Ks = (const char*)smem + buf * 65536 + p * 16384;
        const char* Vs = (const char*)smem + buf * 65536 + 32768;
        int k0 = kbase + 32 * p;
        int qg = q0 + ln;
        // ---- QK^T (swapped): s = K * Q; 2 chains ----
        f32x16 sA, sB;
        #pragma unroll
        for (int r = 0; r < 16; r++) { sA[r] = 0.f; sB[r] = 0.f; }
        __builtin_amdgcn_s_setprio(1);
        #pragma unroll
        for (int dc = 0; dc < 16; dc += 2) {
            int kb0 = (dc * 32 + hi * 16) ^ ((ln & 7) << 4);
            int kb1 = ((dc + 1) * 32 + hi * 16) ^ ((ln & 7) << 4);
            bf16x8 kf0 = *(const bf16x8*)(Ks + ln * 512 + kb0);
            bf16x8 kf1 = *(const bf16x8*)(Ks + ln * 512 + kb1);
            sA = __builtin_amdgcn_mfma_f32_32x32x16_bf16(kf0, qf[dc],     sA, 0, 0, 0);
            sB = __builtin_amdgcn_mfma_f32_32x32x16_bf16(kf1, qf[dc + 1], sB, 0, 0, 0);
        }
        __builtin_amdgcn_s_setprio(0);
        f32x16 s;
        #pragma unroll
        for (int r = 0; r < 16; r++) s[r] = sA[r] + sB[r];

        // ---- mask + online softmax, in-register ----
        if (k0 + 31 > q0) {
            #pragma unroll
            for (int r = 0; r < 16; r++) {
                int key_g = k0 + (r & 3) + 8 * (r >> 2) + 4 * hi;
                if (key_g > qg) s[r] = -1e30f;
            }
        }
        float mt = s[0];
        #pragma unroll
        for (int r = 1; r < 16; r++) mt = fmaxf(mt, s[r]);
        mt = fmaxf(mt, __shfl_xor(mt, 32));
        float mn = m;
        if (!__all(mt <= m + 8.f)) {           // defer-max (T13)
            mn = fmaxf(m, mt);
            float f = __expf(m - mn);
            m = mn;
            float fr[16];
            #pragma unroll
            for (int r = 0; r < 16; r++)
                fr[r] = bperm((r & 3) + 8 * (r >> 2) + 4 * hi, f);
            #pragma unroll
            for (int i = 0; i < 8; i++)
                #pragma unroll
                for (int r = 0; r < 16; r++) acc[i][r] *= fr[r];
            l *= f;
        }
        float pr[16], ps = 0.f;
        #pragma unroll
        for (int r = 0; r < 16; r++) { pr[r] = __expf(s[r] - mn); ps += pr[r]; }
        ps += __shfl_xor(ps, 32);
        l += ps;

        // ---- P -> bf16 A-frags (T12) ----
        unsigned pw[8];
        #pragma unroll
        for (int kc = 0; kc < 2; kc++) {
            unsigned X = cvtpk(pr[kc * 8 + 0], pr[kc * 8 + 1]);
            unsigned Y = cvtpk(pr[kc * 8 + 4], pr[kc * 8 + 5]);
            unsigned Z = cvtpk(pr[kc * 8 + 2], pr[kc * 8 + 3]);
            unsigned W = cvtpk(pr[kc * 8 + 6], pr[kc * 8 + 7]);
            asm volatile("v_permlane32_swap_b32 %0, %1" : "+v"(X), "+v"(Y));
            asm volatile("v_permlane32_swap_b32 %0, %1" : "+v"(Z), "+v"(W));
            pw[kc * 4 + 0] = X; pw[kc * 4 + 1] = Z;
            pw[kc * 4 + 2] = Y; pw[kc * 4 + 3] = W;
        }
        u32x4 w0v = {pw[0], pw[1], pw[2], pw[3]};
        u32x4 w1v = {pw[4], pw[5], pw[6], pw[7]};
        bf16x8 pa0 = __builtin_bit_cast(bf16x8, w0v);
        bf16x8 pa1 = __builtin_bit_cast(bf16x8, w1v);

        // ---- PV over this wave's 32 keys (parity half of 128B V rows) ----
        __builtin_amdgcn_s_setprio(1);
        #pragma unroll
        for (int db = 0; db < 8; db++) {
            int drow = db * 32 + ln;
            int sw = (drow & 7) << 4;
            bf16x8 vf0 = *(const bf16x8*)(Vs + drow * 128 + ((p * 64 + hi * 16) ^ sw));
            bf16x8 vf1 = *(const bf16x8*)(Vs + drow * 128 + ((p * 64 + 32 + hi * 16) ^ sw));
            acc[db] = __builtin_amdgcn_mfma_f32_32x32x16_bf16(pa0, vf0, acc[db], 0, 0, 0);
            acc[db] = __builtin_amdgcn_mfma_f32_32x32x16_bf16(pa1, vf1, acc[db], 0, 0, 0);
        }
        __builtin_amdgcn_s_setprio(0);
    };

    auto merge_store = [&](int j) {
        float* accb = (float*)(smem + 131072);
        float* mlb  = (float*)(smem + 147456);
        int q0l = j * 128 + g * 32;
        float fr0[16], fr1[16];
        for (int gr = 0; gr < 4; gr++)
        for (int hs = 0; hs < 2; hs++) {
            __syncthreads();
            if (g == gr && p == 1) {
                #pragma unroll
                for (int dbl = 0; dbl < 4; dbl++)
                    #pragma unroll
                    for (int r = 0; r < 16; r++)
                        accb[(dbl * 16 + r) * 64 + hi * 32 + ln] = acc[hs * 4 + dbl][r];
                if (hs == 0 && hi == 0) { mlb[ln] = m; mlb[32 + ln] = l; }
            }
            __syncthreads();
            if (g == gr && p == 0) {
                if (hs == 0) {
                    float m1 = mlb[ln], l1 = mlb[32 + ln];
                    float M = fmaxf(m, m1);
                    float f0 = __expf(m - M), f1 = __expf(m1 - M);
                    float lt = l * f0 + l1 * f1;
                    float w0 = f0 / lt, w1 = f1 / lt;
                    #pragma unroll
                    for (int r = 0; r < 16; r++) {
                        int crow = (r & 3) + 8 * (r >> 2) + 4 * hi;
                        fr0[r] = bperm(crow, w0);
                        fr1[r] = bperm(crow, w1);
                    }
                }
                #pragma unroll
                for (int dbl = 0; dbl < 4; dbl++)
                    #pragma unroll
                    for (int r = 0; r < 16; r++) {
                        int db = hs * 4 + dbl;
                        float a1 = accb[(dbl * 16 + r) * 64 + hi * 32 + ln];
                        int qrow = q0l + (r & 3) + 8 * (r >> 2) + 4 * hi;
                        O[(long)(b * S_LEN + qrow) * 2048 + h * HD + db * 32 + ln] =
                            f2bf(acc[db][r] * fr0[r] + a1 * fr1[r]);
                    }
            }
        }
    };

    // keybase of flat phase f
    auto kbase_of = [&](int f) { return 64 * ((f < nphA) ? f : (f - nphA)); };

    stage(0, kbase_of(0));
    stage(1, kbase_of(1));
    qnorm(jA);
    #pragma unroll
    for (int i = 0; i < 8; i++)
        #pragma unroll
        for (int r = 0; r < 16; r++) acc[i][r] = 0.f;
    m = -1e30f; l = 0.f;

    for (int f = 0; f < nt; f++) {
        int buf = f & 1;
        int j = (f < nphA) ? jA : jB;
        int q0 = j * 128 + g * 32;
        int kb = kbase_of(f);
        if (f == nt - 1) { asm volatile("s_waitcnt vmcnt(0)" ::: "memory"); }
        else             { asm volatile("s_waitcnt vmcnt(8)" ::: "memory"); }
        __builtin_amdgcn_s_barrier();
        if (kb + 32 * p <= q0 + 31) compute(buf, kb, q0);
        __builtin_amdgcn_s_barrier();
        if (f + 2 < nt) stage(buf, kbase_of(f + 2));
        __builtin_amdgcn_sched_barrier(0);
        if (f == nphA - 1) {                 // chunk A done: merge, reset, re-Q
            merge_store(jA);
            #pragma unroll
            for (int i = 0; i < 8; i++)
                #pragma unroll
                for (int r = 0; r < 16; r++) acc[i][r] = 0.f;
            m = -1e30f; l = 0.f;
            qnorm(jB);
        }
    }
    merge_store(jB);
}

extern "C" void kernel_launch(void* const* d_in, const int* in_sizes, int n_in,
                              void* d_out, int out_size, void* d_ws, size_t ws_size,
                              hipStream_t stream) {
    const float* x    = (const float*)d_in[0];
    const float* cosb = (const float*)d_in[1];
    const float* sinb = (const float*)d_in[2];
    // d_in[3] = mask: equivalent to causal; computed analytically in-kernel
    const float* wq   = (const float*)d_in[4];
    const float* wk   = (const float*)d_in[5];
    const float* wv   = (const float*)d_in[6];
    const float* wo   = (const float*)d_in[7];
    const float* qnw  = (const float*)d_in[8];
    const float* knw  = (const float*)d_in[9];
    float* out = (float*)d_out;

    char* ws = (char*)d_ws;
    short* xb   = (short*)(ws + 0);          // 4096x512 bf16               [0, 4194304)
    short* wfus = (short*)(ws + 4194304);    // [3072][512] wq|wk|wv^T      [4194304, 7340032)
    short* wot  = (short*)(ws + 7340032);    // [512][2048] wo^T            [7340032, 9437184)
    short* C    = (short*)(ws + 9437184);    // 4096x3072 fused QKV out     [9437184, 34603008)
    short* ao   = (short*)(ws + 34603008);   // flash out (C stays live: Q source)
    short* kr   = (short*)(ws + 51380224);   // [b][kv][s][d] 4 MB          [51380224, 55574528)
    short* vr   = (short*)(ws + 55574528);   // [b][kv][d][s] 4 MB          [55574528, 59768832)

    cvt_kernel<<<2048, 256, 0, stream>>>(x, xb, 2097152);
    wt_kernel<<<dim3(32, 8), 256, 0, stream>>>(wq, wfus,              512, 2048);
    wt_kernel<<<dim3(8, 8),  256, 0, stream>>>(wk, wfus + 2048 * 512, 512, 512);
    wt_kernel<<<dim3(8, 8),  256, 0, stream>>>(wv, wfus + 2560 * 512, 512, 512);
    wt_kernel<<<dim3(8, 32), 256, 0, stream>>>(wo, wot, 2048, 512);

    // fused QKV projection: C[4096][3072]
    gemm_bt<128, 1><<<dim3(24, 32), 256, 0, stream>>>(xb, wfus, C, 4096, 3072, 512);

    // K norm+rope -> kr ; V transpose -> vr (Q norm+rope fused into flash)
    norm_rope_kernel<<<2048, 256, 0, stream>>>(C, kr, knw, cosb, sinb, 2,
                                               3072L, 2048L, 1048576L, 524288L, 256L, 1.0f);
    transpose_v_kernel<<<dim3(32, 4, 4), 256, 0, stream>>>(C, vr);

    flash_kernel<<<256, 512, 0, stream>>>(C, kr, vr, ao, qnw, cosb, sinb);

    gemm_bt<64, 0><<<dim3(8, 32), 256, 0, stream>>>(ao, wot, out, 4096, 512, 2048);
}

// Round 11
// 684.164 us; speedup vs baseline: 1.4695x; 1.4695x over previous
//
#include <hip/hip_runtime.h>

#define S_LEN 2048
#define NHQ 8
#define NKV 2
#define HD 256

typedef __attribute__((ext_vector_type(8))) short bf16x8;
typedef __attribute__((ext_vector_type(4))) short bf16x4;
typedef __attribute__((ext_vector_type(4))) float f32x4;
typedef __attribute__((ext_vector_type(16))) float f32x16;
typedef __attribute__((ext_vector_type(4))) unsigned u32x4;

__device__ __forceinline__ short f2bf(float f) {
    unsigned u = __builtin_bit_cast(unsigned, f);
    u += 0x7FFFu + ((u >> 16) & 1u);
    return (short)(u >> 16);
}
__device__ __forceinline__ float bf2f(short s) {
    unsigned u = ((unsigned)(unsigned short)s) << 16;
    return __builtin_bit_cast(float, u);
}
__device__ __forceinline__ unsigned cvtpk(float a, float b) {
    unsigned r;
    asm("v_cvt_pk_bf16_f32 %0, %1, %2" : "=v"(r) : "v"(a), "v"(b));
    return r;
}
__device__ __forceinline__ void gload16(const short* g, short* l) {
    __builtin_amdgcn_global_load_lds((const __attribute__((address_space(1))) unsigned*)g,
                                     (__attribute__((address_space(3))) unsigned*)l, 16, 0, 0);
}
__device__ __forceinline__ float bperm(int srclane, float v) {
    return __builtin_bit_cast(float,
        __builtin_amdgcn_ds_bpermute(srclane * 4, __builtin_bit_cast(int, v)));
}

// ---------------- fp32 -> bf16 convert ----------------
__global__ __launch_bounds__(256) void cvt_kernel(const float* __restrict__ in,
                                                  short* __restrict__ out, int n) {
    int i = (blockIdx.x * 256 + threadIdx.x) * 4;
    if (i + 3 < n) {
        float4 f = *(const float4*)(in + i);
        bf16x4 o;
        o[0] = f2bf(f.x); o[1] = f2bf(f.y); o[2] = f2bf(f.z); o[3] = f2bf(f.w);
        *(bf16x4*)(out + i) = o;
    }
}

// ---------------- fp32 W[K][N] -> bf16 Wt[N][K] (convert + transpose) -------
__global__ __launch_bounds__(256) void wt_kernel(const float* __restrict__ in,
                                                 short* __restrict__ out,
                                                 int K, int N) {
    __shared__ short tile[64][72];
    int n0 = blockIdx.x * 64, k0 = blockIdx.y * 64;
    int t = threadIdx.x;
    #pragma unroll
    for (int i = 0; i < 16; i++) {
        int flat = i * 256 + t; int r = flat >> 6, c = flat & 63;
        tile[r][c] = f2bf(in[(long)(k0 + r) * N + n0 + c]);
    }
    __syncthreads();
    #pragma unroll
    for (int i = 0; i < 16; i++) {
        int flat = i * 256 + t; int r = flat >> 6, c = flat & 63;
        out[(long)(n0 + r) * K + k0 + c] = tile[c][r];
    }
}

// ---------------- m97-style GEMM: C[M][N] = A[M][K] @ Bt[N][K]^T ------------
template<int BN, int WRITE_BF16>
__global__ __launch_bounds__(256) void gemm_bt(const short* __restrict__ A,
                                               const short* __restrict__ Bt,
                                               void* __restrict__ Cv,
                                               int M, int N, int K) {
    constexpr int NI = BN / 32;          // B-frags per wave
    __shared__ short As[128 * 32];
    __shared__ short Bs[BN * 32];
    const int t = threadIdx.x;
    const int lane = t & 63, w = t >> 6;
    const int lr = lane & 15, lg = lane >> 4;
    const int m0 = blockIdx.y * 128, n0 = blockIdx.x * BN;
    const int wm = (w >> 1) * 64, wn = (w & 1) * (BN / 2);

    f32x4 acc[4][NI];
    #pragma unroll
    for (int i = 0; i < 4; i++)
        #pragma unroll
        for (int j = 0; j < NI; j++) acc[i][j] = (f32x4){0.f, 0.f, 0.f, 0.f};

    for (int k0 = 0; k0 < K; k0 += 32) {
        __syncthreads();
        #pragma unroll
        for (int r = 0; r < 2; r++) {            // A tile: 128x32 = 8 KB
            int sbase = r * 2048 + w * 512;
            int srow = (sbase + lane * 8) >> 5, scol = (sbase + lane * 8) & 31;
            gload16(A + (long)(m0 + srow) * K + k0 + scol, &As[sbase]);
        }
        #pragma unroll
        for (int r = 0; r < BN / 64; r++) {      // B tile: BNx32
            int sbase = r * 2048 + w * 512;
            int srow = (sbase + lane * 8) >> 5, scol = (sbase + lane * 8) & 31;
            gload16(Bt + (long)(n0 + srow) * K + k0 + scol, &Bs[sbase]);
        }
        __syncthreads();
        bf16x8 af[4], bfr[NI];
        #pragma unroll
        for (int mi = 0; mi < 4; mi++)
            af[mi] = *(const bf16x8*)&As[(wm + mi * 16 + lr) * 32 + lg * 8];
        #pragma unroll
        for (int ni = 0; ni < NI; ni++)
            bfr[ni] = *(const bf16x8*)&Bs[(wn + ni * 16 + lr) * 32 + lg * 8];
        #pragma unroll
        for (int mi = 0; mi < 4; mi++)
            #pragma unroll
            for (int ni = 0; ni < NI; ni++)
                acc[mi][ni] = __builtin_amdgcn_mfma_f32_16x16x32_bf16(af[mi], bfr[ni], acc[mi][ni], 0, 0, 0);
    }
    #pragma unroll
    for (int mi = 0; mi < 4; mi++)
    #pragma unroll
    for (int ni = 0; ni < NI; ni++)
    #pragma unroll
    for (int r = 0; r < 4; r++) {
        long row = m0 + wm + mi * 16 + lg * 4 + r;
        long col = n0 + wn + ni * 16 + lr;
        float v = acc[mi][ni][r];
        if (WRITE_BF16) ((short*)Cv)[row * N + col] = f2bf(v);
        else            ((float*)Cv)[row * N + col] = v;
    }
}

// ---------------- RMSNorm + partial RoPE (K path) ---------------------------
__global__ __launch_bounds__(256) void norm_rope_kernel(
    const short* __restrict__ in, short* __restrict__ out,
    const float* __restrict__ w, const float* __restrict__ cosb,
    const float* __restrict__ sinb, int H, long ldin, long cofs,
    long ob, long oh, long os, float scale) {
    int vec = blockIdx.x * 4 + (threadIdx.x >> 6);
    int lane = threadIdx.x & 63;
    int token = vec / H, head = vec % H;
    int b = token / S_LEN, s = token % S_LEN;

    bf16x4 xv = *(const bf16x4*)(in + (long)token * ldin + cofs + head * 256 + lane * 4);
    float x0 = bf2f(xv[0]), x1 = bf2f(xv[1]), x2 = bf2f(xv[2]), x3 = bf2f(xv[3]);
    float ss = x0 * x0 + x1 * x1 + x2 * x2 + x3 * x3;
    #pragma unroll
    for (int m = 1; m < 64; m <<= 1) ss += __shfl_xor(ss, m);
    float inv = rsqrtf(ss * (1.f / 256.f) + 1e-6f);

    float4 wv = *(const float4*)(w + lane * 4);
    float y0 = x0 * inv * (1.f + wv.x);
    float y1 = x1 * inv * (1.f + wv.y);
    float y2 = x2 * inv * (1.f + wv.z);
    float y3 = x3 * inv * (1.f + wv.w);

    if (lane < 16) {
        float2 c = *(const float2*)&cosb[s * 32 + lane * 2];
        float2 sn = *(const float2*)&sinb[s * 32 + lane * 2];
        float a0 = y0 * c.x - y1 * sn.x, b0 = y0 * sn.x + y1 * c.x;
        float a1 = y2 * c.y - y3 * sn.y, b1 = y2 * sn.y + y3 * c.y;
        y0 = a0; y1 = b0; y2 = a1; y3 = b1;
    }
    y0 *= scale; y1 *= scale; y2 *= scale; y3 *= scale;
    long oidx = (long)b * ob + (long)head * oh + (long)s * os + lane * 4;
    bf16x4 o; o[0] = f2bf(y0); o[1] = f2bf(y1); o[2] = f2bf(y2); o[3] = f2bf(y3);
    *(bf16x4*)(out + oidx) = o;
}

// ---------------- V transpose: C[token][2560+kv*256+d] -> vr[b][kv][d][s] ---
__global__ __launch_bounds__(256) void transpose_v_kernel(const short* __restrict__ C,
                                                          short* __restrict__ vr) {
    __shared__ short tile[64][65];
    int s0 = blockIdx.x * 64, d0 = blockIdx.y * 64;
    int bkv = blockIdx.z; int b = bkv >> 1, kv = bkv & 1;
    int t = threadIdx.x;
    #pragma unroll
    for (int i = 0; i < 16; i++) {
        int flat = i * 256 + t; int si = flat >> 6, di = flat & 63;
        tile[si][di] = C[(long)(b * S_LEN + s0 + si) * 3072 + 2560 + kv * 256 + d0 + di];
    }
    __syncthreads();
    #pragma unroll
    for (int i = 0; i < 16; i++) {
        int flat = i * 256 + t; int di = flat >> 6, si = flat & 63;
        vr[(long)(bkv * 256 + d0 + di) * S_LEN + s0 + si] = tile[si][di];
    }
}

// ---------------- flash attention: 8 waves, 1 block/CU, 34 uniform phases ---
// Block = chunk pair (15-c, c) of 128 q-rows each, processed sequentially.
// Waves: 4 q-groups x 2 key parities. Phase = 64 keys, true double buffer,
// counted vmcnt(8) -> loads span 2 phases. Q norm+rope fused (per chunk).
// NOTE: all acc[] indices MUST be compile-time (rule #20) else acc -> scratch.
__global__ __launch_bounds__(512, 1) void flash_kernel(const short* __restrict__ Cq,
                                                       const short* __restrict__ Kt,
                                                       const short* __restrict__ Vt,
                                                       short* __restrict__ O,
                                                       const float* __restrict__ qnw,
                                                       const float* __restrict__ cosb,
                                                       const float* __restrict__ sinb) {
    // buf i at i*65536: K 64x512B (swz (key&7)<<4) + V 256x128B (swz (d&7)<<4)
    // scratch at 131072 (16 KB acc rounds), ml at 147456. Total 147968.
    __shared__ __align__(16) char smem[147968];

    int idx = blockIdx.x;
    int xcd = idx & 7, r5 = idx >> 3;
    int bh = xcd * 2 + (r5 & 1);             // per-XCD KV slice = 2 MB (L2-fit)
    int c  = r5 >> 1;                        // 0..15
    int jA = 15 - c, jB = c;                 // chunk pair: 34 phases total, uniform
    int h = bh & 7, b = bh >> 3;
    int kv = h >> 2;
    int t = threadIdx.x, lane = t & 63, w = t >> 6;
    int g = w >> 1, p = w & 1;               // q-group (32 rows), key parity
    int ln = lane & 31, hi = lane >> 5;

    const short* Kb = Kt + (long)(b * NKV + kv) * S_LEN * HD;
    const short* Vb = Vt + (long)(b * NKV + kv) * HD * S_LEN;

    const int nphA = 2 * (jA + 1), nphB = 2 * (jB + 1);
    const int nt = nphA + nphB;              // == 34

    // stage 64-key tile pair at absolute key base kbase into buf (8 loads/thr)
    auto stage = [&](int buf, int kbase) {
        short* Kt0 = (short*)(smem + buf * 65536);
        short* Vt0 = (short*)(smem + buf * 65536 + 32768);
        #pragma unroll
        for (int cc = 0; cc < 4; cc++) {
            int o = cc * 8192 + w * 1024 + lane * 16;
            int key = o >> 9, db = o & 511;
            gload16(Kb + (long)(kbase + key) * HD + ((db ^ ((key & 7) << 4)) >> 1),
                    Kt0 + (cc * 8192 + w * 1024) / 2);
            int d = o >> 7, kb = o & 127;
            gload16(Vb + (long)d * S_LEN + kbase + ((kb ^ ((d & 7) << 4)) >> 1),
                    Vt0 + (cc * 8192 + w * 1024) / 2);
        }
    };

    bf16x8 qf[16];
    f32x16 acc[8];
    float m, l;

    auto qnorm = [&](int j) {
        int qgl = j * 128 + g * 32 + ln;
        const short* qrow = Cq + (long)(b * S_LEN + qgl) * 3072 + h * 256 + hi * 8;
        #pragma unroll
        for (int dc = 0; dc < 16; dc++) qf[dc] = *(const bf16x8*)&qrow[dc * 16];
        float ss = 0.f;
        #pragma unroll
        for (int dc = 0; dc < 16; dc++)
            #pragma unroll
            for (int e = 0; e < 8; e++) { float v = bf2f(qf[dc][e]); ss += v * v; }
        ss += __shfl_xor(ss, 32);
        float inv = rsqrtf(ss * (1.f / 256.f) + 1e-6f);
        #pragma unroll
        for (int dc = 0; dc < 16; dc++) {
            float y[8];
            float4 w0 = *(const float4*)&qnw[dc * 16 + hi * 8];
            float4 w1 = *(const float4*)&qnw[dc * 16 + hi * 8 + 4];
            y[0] = bf2f(qf[dc][0]) * inv * (1.f + w0.x);
            y[1] = bf2f(qf[dc][1]) * inv * (1.f + w0.y);
            y[2] = bf2f(qf[dc][2]) * inv * (1.f + w0.z);
            y[3] = bf2f(qf[dc][3]) * inv * (1.f + w0.w);
            y[4] = bf2f(qf[dc][4]) * inv * (1.f + w1.x);
            y[5] = bf2f(qf[dc][5]) * inv * (1.f + w1.y);
            y[6] = bf2f(qf[dc][6]) * inv * (1.f + w1.z);
            y[7] = bf2f(qf[dc][7]) * inv * (1.f + w1.w);
            if (dc < 4) {   // d < 64: rope pairs (2i,2i+1)
                float4 c4 = *(const float4*)&cosb[qgl * 32 + dc * 8 + hi * 4];
                float4 s4 = *(const float4*)&sinb[qgl * 32 + dc * 8 + hi * 4];
                float a, bb;
                a = y[0]; bb = y[1]; y[0] = a * c4.x - bb * s4.x; y[1] = a * s4.x + bb * c4.x;
                a = y[2]; bb = y[3]; y[2] = a * c4.y - bb * s4.y; y[3] = a * s4.y + bb * c4.y;
                a = y[4]; bb = y[5]; y[4] = a * c4.z - bb * s4.z; y[5] = a * s4.z + bb * c4.z;
                a = y[6]; bb = y[7]; y[6] = a * c4.w - bb * s4.w; y[7] = a * s4.w + bb * c4.w;
            }
            bf16x8 o;
            #pragma unroll
            for (int e = 0; e < 8; e++) o[e] = f2bf(y[e] * 0.0625f);
            qf[dc] = o;
        }
    };

    auto compute = [&](int buf, int kbase, int q0) {
        const char* Ks = (const char*)smem + buf * 65536 + p * 16384;
        const char* Vs = (const char*)smem + buf * 65536 + 32768;
        int k0 = kbase + 32 * p;
        int qg = q0 + ln;
        // ---- QK^T (swapped): s = K * Q; 2 chains ----
        f32x16 sA, sB;
        #pragma unroll
        for (int r = 0; r < 16; r++) { sA[r] = 0.f; sB[r] = 0.f; }
        __builtin_amdgcn_s_setprio(1);
        #pragma unroll
        for (int dc = 0; dc < 16; dc += 2) {
            int kb0 = (dc * 32 + hi * 16) ^ ((ln & 7) << 4);
            int kb1 = ((dc + 1) * 32 + hi * 16) ^ ((ln & 7) << 4);
            bf16x8 kf0 = *(const bf16x8*)(Ks + ln * 512 + kb0);
            bf16x8 kf1 = *(const bf16x8*)(Ks + ln * 512 + kb1);
            sA = __builtin_amdgcn_mfma_f32_32x32x16_bf16(kf0, qf[dc],     sA, 0, 0, 0);
            sB = __builtin_amdgcn_mfma_f32_32x32x16_bf16(kf1, qf[dc + 1], sB, 0, 0, 0);
        }
        __builtin_amdgcn_s_setprio(0);
        f32x16 s;
        #pragma unroll
        for (int r = 0; r < 16; r++) s[r] = sA[r] + sB[r];

        // ---- mask + online softmax, in-register ----
        if (k0 + 31 > q0) {
            #pragma unroll
            for (int r = 0; r < 16; r++) {
                int key_g = k0 + (r & 3) + 8 * (r >> 2) + 4 * hi;
                if (key_g > qg) s[r] = -1e30f;
            }
        }
        float mt = s[0];
        #pragma unroll
        for (int r = 1; r < 16; r++) mt = fmaxf(mt, s[r]);
        mt = fmaxf(mt, __shfl_xor(mt, 32));
        float mn = m;
        if (!__all(mt <= m + 8.f)) {           // defer-max (T13)
            mn = fmaxf(m, mt);
            float f = __expf(m - mn);
            m = mn;
            float fr[16];
            #pragma unroll
            for (int r = 0; r < 16; r++)
                fr[r] = bperm((r & 3) + 8 * (r >> 2) + 4 * hi, f);
            #pragma unroll
            for (int i = 0; i < 8; i++)
                #pragma unroll
                for (int r = 0; r < 16; r++) acc[i][r] *= fr[r];
            l *= f;
        }
        float pr[16], ps = 0.f;
        #pragma unroll
        for (int r = 0; r < 16; r++) { pr[r] = __expf(s[r] - mn); ps += pr[r]; }
        ps += __shfl_xor(ps, 32);
        l += ps;

        // ---- P -> bf16 A-frags (T12) ----
        unsigned pw[8];
        #pragma unroll
        for (int kc = 0; kc < 2; kc++) {
            unsigned X = cvtpk(pr[kc * 8 + 0], pr[kc * 8 + 1]);
            unsigned Y = cvtpk(pr[kc * 8 + 4], pr[kc * 8 + 5]);
            unsigned Z = cvtpk(pr[kc * 8 + 2], pr[kc * 8 + 3]);
            unsigned W = cvtpk(pr[kc * 8 + 6], pr[kc * 8 + 7]);
            asm volatile("v_permlane32_swap_b32 %0, %1" : "+v"(X), "+v"(Y));
            asm volatile("v_permlane32_swap_b32 %0, %1" : "+v"(Z), "+v"(W));
            pw[kc * 4 + 0] = X; pw[kc * 4 + 1] = Z;
            pw[kc * 4 + 2] = Y; pw[kc * 4 + 3] = W;
        }
        u32x4 w0v = {pw[0], pw[1], pw[2], pw[3]};
        u32x4 w1v = {pw[4], pw[5], pw[6], pw[7]};
        bf16x8 pa0 = __builtin_bit_cast(bf16x8, w0v);
        bf16x8 pa1 = __builtin_bit_cast(bf16x8, w1v);

        // ---- PV over this wave's 32 keys (parity half of 128B V rows) ----
        __builtin_amdgcn_s_setprio(1);
        #pragma unroll
        for (int db = 0; db < 8; db++) {
            int drow = db * 32 + ln;
            int sw = (drow & 7) << 4;
            bf16x8 vf0 = *(const bf16x8*)(Vs + drow * 128 + ((p * 64 + hi * 16) ^ sw));
            bf16x8 vf1 = *(const bf16x8*)(Vs + drow * 128 + ((p * 64 + 32 + hi * 16) ^ sw));
            acc[db] = __builtin_amdgcn_mfma_f32_32x32x16_bf16(pa0, vf0, acc[db], 0, 0, 0);
            acc[db] = __builtin_amdgcn_mfma_f32_32x32x16_bf16(pa1, vf1, acc[db], 0, 0, 0);
        }
        __builtin_amdgcn_s_setprio(0);
    };

    auto merge_store = [&](int j) {
        float* accb = (float*)(smem + 131072);
        float* mlb  = (float*)(smem + 147456);
        int q0l = j * 128 + g * 32;
        float fr0[16], fr1[16];
        #pragma unroll                      // rule #20: static acc indices only
        for (int gr = 0; gr < 4; gr++)
        #pragma unroll
        for (int hs = 0; hs < 2; hs++) {
            __syncthreads();
            if (g == gr && p == 1) {
                #pragma unroll
                for (int dbl = 0; dbl < 4; dbl++)
                    #pragma unroll
                    for (int r = 0; r < 16; r++)
                        accb[(dbl * 16 + r) * 64 + hi * 32 + ln] = acc[hs * 4 + dbl][r];
                if (hs == 0 && hi == 0) { mlb[ln] = m; mlb[32 + ln] = l; }
            }
            __syncthreads();
            if (g == gr && p == 0) {
                if (hs == 0) {
                    float m1 = mlb[ln], l1 = mlb[32 + ln];
                    float M = fmaxf(m, m1);
                    float f0 = __expf(m - M), f1 = __expf(m1 - M);
                    float lt = l * f0 + l1 * f1;
                    float w0 = f0 / lt, w1 = f1 / lt;
                    #pragma unroll
                    for (int r = 0; r < 16; r++) {
                        int crow = (r & 3) + 8 * (r >> 2) + 4 * hi;
                        fr0[r] = bperm(crow, w0);
                        fr1[r] = bperm(crow, w1);
                    }
                }
                #pragma unroll
                for (int dbl = 0; dbl < 4; dbl++)
                    #pragma unroll
                    for (int r = 0; r < 16; r++) {
                        float a1 = accb[(dbl * 16 + r) * 64 + hi * 32 + ln];
                        int qrow = q0l + (r & 3) + 8 * (r >> 2) + 4 * hi;
                        O[(long)(b * S_LEN + qrow) * 2048 + h * HD + (hs * 4 + dbl) * 32 + ln] =
                            f2bf(acc[hs * 4 + dbl][r] * fr0[r] + a1 * fr1[r]);
                    }
            }
        }
    };

    // keybase of flat phase f
    auto kbase_of = [&](int f) { return 64 * ((f < nphA) ? f : (f - nphA)); };

    stage(0, kbase_of(0));
    stage(1, kbase_of(1));
    qnorm(jA);
    #pragma unroll
    for (int i = 0; i < 8; i++)
        #pragma unroll
        for (int r = 0; r < 16; r++) acc[i][r] = 0.f;
    m = -1e30f; l = 0.f;

    for (int f = 0; f < nt; f++) {
        int buf = f & 1;
        int j = (f < nphA) ? jA : jB;
        int q0 = j * 128 + g * 32;
        int kb = kbase_of(f);
        if (f == nt - 1) { asm volatile("s_waitcnt vmcnt(0)" ::: "memory"); }
        else             { asm volatile("s_waitcnt vmcnt(8)" ::: "memory"); }
        __builtin_amdgcn_s_barrier();
        if (kb + 32 * p <= q0 + 31) compute(buf, kb, q0);
        __builtin_amdgcn_s_barrier();
        if (f + 2 < nt) stage(buf, kbase_of(f + 2));
        __builtin_amdgcn_sched_barrier(0);
        if (f == nphA - 1) {                 // chunk A done: merge, reset, re-Q
            merge_store(jA);
            #pragma unroll
            for (int i = 0; i < 8; i++)
                #pragma unroll
                for (int r = 0; r < 16; r++) acc[i][r] = 0.f;
            m = -1e30f; l = 0.f;
            qnorm(jB);
        }
    }
    merge_store(jB);
}

extern "C" void kernel_launch(void* const* d_in, const int* in_sizes, int n_in,
                              void* d_out, int out_size, void* d_ws, size_t ws_size,
                              hipStream_t stream) {
    const float* x    = (const float*)d_in[0];
    const float* cosb = (const float*)d_in[1];
    const float* sinb = (const float*)d_in[2];
    // d_in[3] = mask: equivalent to causal; computed analytically in-kernel
    const float* wq   = (const float*)d_in[4];
    const float* wk   = (const float*)d_in[5];
    const float* wv   = (const float*)d_in[6];
    const float* wo   = (const float*)d_in[7];
    const float* qnw  = (const float*)d_in[8];
    const float* knw  = (const float*)d_in[9];
    float* out = (float*)d_out;

    char* ws = (char*)d_ws;
    short* xb   = (short*)(ws + 0);          // 4096x512 bf16               [0, 4194304)
    short* wfus = (short*)(ws + 4194304);    // [3072][512] wq|wk|wv^T      [4194304, 7340032)
    short* wot  = (short*)(ws + 7340032);    // [512][2048] wo^T            [7340032, 9437184)
    short* C    = (short*)(ws + 9437184);    // 4096x3072 fused QKV out     [9437184, 34603008)
    short* ao   = (short*)(ws + 34603008);   // flash out (C stays live: Q source)
    short* kr   = (short*)(ws + 51380224);   // [b][kv][s][d] 4 MB          [51380224, 55574528)
    short* vr   = (short*)(ws + 55574528);   // [b][kv][d][s] 4 MB          [55574528, 59768832)

    cvt_kernel<<<2048, 256, 0, stream>>>(x, xb, 2097152);
    wt_kernel<<<dim3(32, 8), 256, 0, stream>>>(wq, wfus,              512, 2048);
    wt_kernel<<<dim3(8, 8),  256, 0, stream>>>(wk, wfus + 2048 * 512, 512, 512);
    wt_kernel<<<dim3(8, 8),  256, 0, stream>>>(wv, wfus + 2560 * 512, 512, 512);
    wt_kernel<<<dim3(8, 32), 256, 0, stream>>>(wo, wot, 2048, 512);

    // fused QKV projection: C[4096][3072]
    gemm_bt<128, 1><<<dim3(24, 32), 256, 0, stream>>>(xb, wfus, C, 4096, 3072, 512);

    // K norm+rope -> kr ; V transpose -> vr (Q norm+rope fused into flash)
    norm_rope_kernel<<<2048, 256, 0, stream>>>(C, kr, knw, cosb, sinb, 2,
                                               3072L, 2048L, 1048576L, 524288L, 256L, 1.0f);
    transpose_v_kernel<<<dim3(32, 4, 4), 256, 0, stream>>>(C, vr);

    flash_kernel<<<256, 512, 0, stream>>>(C, kr, vr, ao, qnw, cosb, sinb);

    gemm_bt<64, 0><<<dim3(8, 32), 256, 0, stream>>>(ao, wot, out, 4096, 512, 2048);
}

// Round 12
// 498.677 us; speedup vs baseline: 2.0161x; 1.3720x over previous
//
#include <hip/hip_runtime.h>

#define S_LEN 2048
#define NHQ 8
#define NKV 2
#define HD 256

typedef __attribute__((ext_vector_type(8))) short bf16x8;
typedef __attribute__((ext_vector_type(4))) short bf16x4;
typedef __attribute__((ext_vector_type(4))) float f32x4;
typedef __attribute__((ext_vector_type(16))) float f32x16;
typedef __attribute__((ext_vector_type(4))) unsigned u32x4;

__device__ __forceinline__ short f2bf(float f) {
    unsigned u = __builtin_bit_cast(unsigned, f);
    u += 0x7FFFu + ((u >> 16) & 1u);
    return (short)(u >> 16);
}
__device__ __forceinline__ float bf2f(short s) {
    unsigned u = ((unsigned)(unsigned short)s) << 16;
    return __builtin_bit_cast(float, u);
}
__device__ __forceinline__ unsigned cvtpk(float a, float b) {
    unsigned r;
    asm("v_cvt_pk_bf16_f32 %0, %1, %2" : "=v"(r) : "v"(a), "v"(b));
    return r;
}
__device__ __forceinline__ void gload16(const short* g, short* l) {
    __builtin_amdgcn_global_load_lds((const __attribute__((address_space(1))) unsigned*)g,
                                     (__attribute__((address_space(3))) unsigned*)l, 16, 0, 0);
}
__device__ __forceinline__ float bperm(int srclane, float v) {
    return __builtin_bit_cast(float,
        __builtin_amdgcn_ds_bpermute(srclane * 4, __builtin_bit_cast(int, v)));
}

// ---------------- fp32 -> bf16 convert ----------------
__global__ __launch_bounds__(256) void cvt_kernel(const float* __restrict__ in,
                                                  short* __restrict__ out, int n) {
    int i = (blockIdx.x * 256 + threadIdx.x) * 4;
    if (i + 3 < n) {
        float4 f = *(const float4*)(in + i);
        bf16x4 o;
        o[0] = f2bf(f.x); o[1] = f2bf(f.y); o[2] = f2bf(f.z); o[3] = f2bf(f.w);
        *(bf16x4*)(out + i) = o;
    }
}

// ---------------- fp32 W[K][N] -> bf16 Wt[N][K] (convert + transpose) -------
__global__ __launch_bounds__(256) void wt_kernel(const float* __restrict__ in,
                                                 short* __restrict__ out,
                                                 int K, int N) {
    __shared__ short tile[64][72];
    int n0 = blockIdx.x * 64, k0 = blockIdx.y * 64;
    int t = threadIdx.x;
    #pragma unroll
    for (int i = 0; i < 16; i++) {
        int flat = i * 256 + t; int r = flat >> 6, c = flat & 63;
        tile[r][c] = f2bf(in[(long)(k0 + r) * N + n0 + c]);
    }
    __syncthreads();
    #pragma unroll
    for (int i = 0; i < 16; i++) {
        int flat = i * 256 + t; int r = flat >> 6, c = flat & 63;
        out[(long)(n0 + r) * K + k0 + c] = tile[c][r];
    }
}

// ---------------- m97-style GEMM: C[M][N] = A[M][K] @ Bt[N][K]^T ------------
template<int BN, int WRITE_BF16>
__global__ __launch_bounds__(256) void gemm_bt(const short* __restrict__ A,
                                               const short* __restrict__ Bt,
                                               void* __restrict__ Cv,
                                               int M, int N, int K) {
    constexpr int NI = BN / 32;          // B-frags per wave
    __shared__ short As[128 * 32];
    __shared__ short Bs[BN * 32];
    const int t = threadIdx.x;
    const int lane = t & 63, w = t >> 6;
    const int lr = lane & 15, lg = lane >> 4;
    const int m0 = blockIdx.y * 128, n0 = blockIdx.x * BN;
    const int wm = (w >> 1) * 64, wn = (w & 1) * (BN / 2);

    f32x4 acc[4][NI];
    #pragma unroll
    for (int i = 0; i < 4; i++)
        #pragma unroll
        for (int j = 0; j < NI; j++) acc[i][j] = (f32x4){0.f, 0.f, 0.f, 0.f};

    for (int k0 = 0; k0 < K; k0 += 32) {
        __syncthreads();
        #pragma unroll
        for (int r = 0; r < 2; r++) {            // A tile: 128x32 = 8 KB
            int sbase = r * 2048 + w * 512;
            int srow = (sbase + lane * 8) >> 5, scol = (sbase + lane * 8) & 31;
            gload16(A + (long)(m0 + srow) * K + k0 + scol, &As[sbase]);
        }
        #pragma unroll
        for (int r = 0; r < BN / 64; r++) {      // B tile: BNx32
            int sbase = r * 2048 + w * 512;
            int srow = (sbase + lane * 8) >> 5, scol = (sbase + lane * 8) & 31;
            gload16(Bt + (long)(n0 + srow) * K + k0 + scol, &Bs[sbase]);
        }
        __syncthreads();
        bf16x8 af[4], bfr[NI];
        #pragma unroll
        for (int mi = 0; mi < 4; mi++)
            af[mi] = *(const bf16x8*)&As[(wm + mi * 16 + lr) * 32 + lg * 8];
        #pragma unroll
        for (int ni = 0; ni < NI; ni++)
            bfr[ni] = *(const bf16x8*)&Bs[(wn + ni * 16 + lr) * 32 + lg * 8];
        #pragma unroll
        for (int mi = 0; mi < 4; mi++)
            #pragma unroll
            for (int ni = 0; ni < NI; ni++)
                acc[mi][ni] = __builtin_amdgcn_mfma_f32_16x16x32_bf16(af[mi], bfr[ni], acc[mi][ni], 0, 0, 0);
    }
    #pragma unroll
    for (int mi = 0; mi < 4; mi++)
    #pragma unroll
    for (int ni = 0; ni < NI; ni++)
    #pragma unroll
    for (int r = 0; r < 4; r++) {
        long row = m0 + wm + mi * 16 + lg * 4 + r;
        long col = n0 + wn + ni * 16 + lr;
        float v = acc[mi][ni][r];
        if (WRITE_BF16) ((short*)Cv)[row * N + col] = f2bf(v);
        else            ((float*)Cv)[row * N + col] = v;
    }
}

// ---------------- RMSNorm + partial RoPE (K path) ---------------------------
__global__ __launch_bounds__(256) void norm_rope_kernel(
    const short* __restrict__ in, short* __restrict__ out,
    const float* __restrict__ w, const float* __restrict__ cosb,
    const float* __restrict__ sinb, int H, long ldin, long cofs,
    long ob, long oh, long os, float scale) {
    int vec = blockIdx.x * 4 + (threadIdx.x >> 6);
    int lane = threadIdx.x & 63;
    int token = vec / H, head = vec % H;
    int b = token / S_LEN, s = token % S_LEN;

    bf16x4 xv = *(const bf16x4*)(in + (long)token * ldin + cofs + head * 256 + lane * 4);
    float x0 = bf2f(xv[0]), x1 = bf2f(xv[1]), x2 = bf2f(xv[2]), x3 = bf2f(xv[3]);
    float ss = x0 * x0 + x1 * x1 + x2 * x2 + x3 * x3;
    #pragma unroll
    for (int m = 1; m < 64; m <<= 1) ss += __shfl_xor(ss, m);
    float inv = rsqrtf(ss * (1.f / 256.f) + 1e-6f);

    float4 wv = *(const float4*)(w + lane * 4);
    float y0 = x0 * inv * (1.f + wv.x);
    float y1 = x1 * inv * (1.f + wv.y);
    float y2 = x2 * inv * (1.f + wv.z);
    float y3 = x3 * inv * (1.f + wv.w);

    if (lane < 16) {
        float2 c = *(const float2*)&cosb[s * 32 + lane * 2];
        float2 sn = *(const float2*)&sinb[s * 32 + lane * 2];
        float a0 = y0 * c.x - y1 * sn.x, b0 = y0 * sn.x + y1 * c.x;
        float a1 = y2 * c.y - y3 * sn.y, b1 = y2 * sn.y + y3 * c.y;
        y0 = a0; y1 = b0; y2 = a1; y3 = b1;
    }
    y0 *= scale; y1 *= scale; y2 *= scale; y3 *= scale;
    long oidx = (long)b * ob + (long)head * oh + (long)s * os + lane * 4;
    bf16x4 o; o[0] = f2bf(y0); o[1] = f2bf(y1); o[2] = f2bf(y2); o[3] = f2bf(y3);
    *(bf16x4*)(out + oidx) = o;
}

// ---------------- V transpose: C[token][2560+kv*256+d] -> vr[b][kv][d][s] ---
__global__ __launch_bounds__(256) void transpose_v_kernel(const short* __restrict__ C,
                                                          short* __restrict__ vr) {
    __shared__ short tile[64][65];
    int s0 = blockIdx.x * 64, d0 = blockIdx.y * 64;
    int bkv = blockIdx.z; int b = bkv >> 1, kv = bkv & 1;
    int t = threadIdx.x;
    #pragma unroll
    for (int i = 0; i < 16; i++) {
        int flat = i * 256 + t; int si = flat >> 6, di = flat & 63;
        tile[si][di] = C[(long)(b * S_LEN + s0 + si) * 3072 + 2560 + kv * 256 + d0 + di];
    }
    __syncthreads();
    #pragma unroll
    for (int i = 0; i < 16; i++) {
        int flat = i * 256 + t; int di = flat >> 6, si = flat & 63;
        vr[(long)(bkv * 256 + d0 + di) * S_LEN + s0 + si] = tile[si][di];
    }
}

// stage 64-key K/V tile at key base kbase into buf (8 loads/thread)
__device__ __forceinline__ void stage_kv(const short* __restrict__ Kb,
                                         const short* __restrict__ Vb,
                                         char* smem, int buf, int kbase,
                                         int w, int lane) {
    short* Kt0 = (short*)(smem + buf * 65536);
    short* Vt0 = (short*)(smem + buf * 65536 + 32768);
    #pragma unroll
    for (int cc = 0; cc < 4; cc++) {
        int o = cc * 8192 + w * 1024 + lane * 16;
        int key = o >> 9, db = o & 511;
        gload16(Kb + (long)(kbase + key) * HD + ((db ^ ((key & 7) << 4)) >> 1),
                Kt0 + (cc * 8192 + w * 1024) / 2);
        int d = o >> 7, kb = o & 127;
        gload16(Vb + (long)d * S_LEN + kbase + ((kb ^ ((d & 7) << 4)) >> 1),
                Vt0 + (cc * 8192 + w * 1024) / 2);
    }
}

// merge half HS (literal!) of acc across key parities for q-group gr.
// rule #20: HS is a macro literal so all acc[] indices are compile-time.
#define MERGE_HALF(HS)                                                         \
  {                                                                            \
    __syncthreads();                                                           \
    if (g == gr && p == 1) {                                                   \
      _Pragma("unroll")                                                        \
      for (int dbl = 0; dbl < 4; dbl++)                                        \
        _Pragma("unroll")                                                      \
        for (int r = 0; r < 16; r++)                                           \
          accb[(dbl * 16 + r) * 64 + hi * 32 + ln] = acc[HS * 4 + dbl][r];     \
      if (HS == 0 && hi == 0) { mlb[ln] = m; mlb[32 + ln] = l; }               \
    }                                                                          \
    __syncthreads();                                                           \
    if (g == gr && p == 0) {                                                   \
      if (HS == 0) {                                                           \
        float m1 = mlb[ln], l1 = mlb[32 + ln];                                 \
        float M = fmaxf(m, m1);                                                \
        float f0 = __expf(m - M), f1 = __expf(m1 - M);                         \
        float lt = l * f0 + l1 * f1;                                           \
        float w0 = f0 / lt, w1 = f1 / lt;                                      \
        _Pragma("unroll")                                                      \
        for (int r = 0; r < 16; r++) {                                         \
          int crow = (r & 3) + 8 * (r >> 2) + 4 * hi;                          \
          fr0[r] = bperm(crow, w0);                                            \
          fr1[r] = bperm(crow, w1);                                            \
        }                                                                      \
      }                                                                        \
      _Pragma("unroll")                                                        \
      for (int dbl = 0; dbl < 4; dbl++)                                        \
        _Pragma("unroll")                                                      \
        for (int r = 0; r < 16; r++) {                                         \
          float a1 = accb[(dbl * 16 + r) * 64 + hi * 32 + ln];                 \
          int qrow = q0 + (r & 3) + 8 * (r >> 2) + 4 * hi;                     \
          O[(long)(b * S_LEN + qrow) * 2048 + h * HD + (HS * 4 + dbl) * 32 + ln] = \
              f2bf(acc[HS * 4 + dbl][r] * fr0[r] + a1 * fr1[r]);               \
        }                                                                      \
    }                                                                          \
  }

// ---------------- flash attention: 8 waves, 1 block/CU, 34 uniform phases ---
// Chunk pair (15-c, c) of 128 q-rows each, sequential. 4 q-groups x 2 key
// parities. Phase = 64 keys, true dbuf, vmcnt(8) -> loads span 2 phases.
// NO lambdas; all acc[] indices compile-time (rule #20).
__global__ __launch_bounds__(512, 1) void flash_kernel(const short* __restrict__ Cq,
                                                       const short* __restrict__ Kt,
                                                       const short* __restrict__ Vt,
                                                       short* __restrict__ O,
                                                       const float* __restrict__ qnw,
                                                       const float* __restrict__ cosb,
                                                       const float* __restrict__ sinb) {
    // buf i at i*65536: K 64x512B (swz (key&7)<<4) + V 256x128B (swz (d&7)<<4)
    // scratch at 131072 (16 KB acc rounds), ml at 147456. Total 147968.
    __shared__ __align__(16) char smem[147968];

    int idx = blockIdx.x;
    int xcd = idx & 7, r5 = idx >> 3;
    int bh = xcd * 2 + (r5 & 1);             // per-XCD KV slice = 2 MB (L2-fit)
    int c  = r5 >> 1;                        // 0..15
    int jA = 15 - c, jB = c;                 // chunk pair: 34 phases, uniform
    int h = bh & 7, b = bh >> 3;
    int kv = h >> 2;
    int t = threadIdx.x, lane = t & 63, w = t >> 6;
    int g = w >> 1, p = w & 1;               // q-group (32 rows), key parity
    int ln = lane & 31, hi = lane >> 5;

    const short* Kb = Kt + (long)(b * NKV + kv) * S_LEN * HD;
    const short* Vb = Vt + (long)(b * NKV + kv) * HD * S_LEN;

    const int nphA = 2 * (jA + 1);
    const int nt = nphA + 2 * (jB + 1);      // == 34

    bf16x8 qf[16];
    f32x16 acc[8];
    float m, l;

    stage_kv(Kb, Vb, smem, 0, 0, w, lane);
    stage_kv(Kb, Vb, smem, 1, 64, w, lane);

    for (int f = 0; f < nt; f++) {
        const int inB = (f >= nphA);
        const int j  = inB ? jB : jA;
        const int q0 = j * 128 + g * 32;
        const int qg = q0 + ln;

        // ---- chunk start: reset state + Q load/norm/rope (inline, once) ----
        if (f == 0 || f == nphA) {
            #pragma unroll
            for (int i = 0; i < 8; i++)
                #pragma unroll
                for (int r = 0; r < 16; r++) acc[i][r] = 0.f;
            m = -1e30f; l = 0.f;
            const short* qrow = Cq + (long)(b * S_LEN + qg) * 3072 + h * 256 + hi * 8;
            #pragma unroll
            for (int dc = 0; dc < 16; dc++) qf[dc] = *(const bf16x8*)&qrow[dc * 16];
            float ss = 0.f;
            #pragma unroll
            for (int dc = 0; dc < 16; dc++)
                #pragma unroll
                for (int e = 0; e < 8; e++) { float v = bf2f(qf[dc][e]); ss += v * v; }
            ss += __shfl_xor(ss, 32);
            float inv = rsqrtf(ss * (1.f / 256.f) + 1e-6f);
            #pragma unroll
            for (int dc = 0; dc < 16; dc++) {
                float y[8];
                float4 w0 = *(const float4*)&qnw[dc * 16 + hi * 8];
                float4 w1 = *(const float4*)&qnw[dc * 16 + hi * 8 + 4];
                y[0] = bf2f(qf[dc][0]) * inv * (1.f + w0.x);
                y[1] = bf2f(qf[dc][1]) * inv * (1.f + w0.y);
                y[2] = bf2f(qf[dc][2]) * inv * (1.f + w0.z);
                y[3] = bf2f(qf[dc][3]) * inv * (1.f + w0.w);
                y[4] = bf2f(qf[dc][4]) * inv * (1.f + w1.x);
                y[5] = bf2f(qf[dc][5]) * inv * (1.f + w1.y);
                y[6] = bf2f(qf[dc][6]) * inv * (1.f + w1.z);
                y[7] = bf2f(qf[dc][7]) * inv * (1.f + w1.w);
                if (dc < 4) {   // d < 64: rope pairs (2i,2i+1)
                    float4 c4 = *(const float4*)&cosb[qg * 32 + dc * 8 + hi * 4];
                    float4 s4 = *(const float4*)&sinb[qg * 32 + dc * 8 + hi * 4];
                    float a, bb;
                    a = y[0]; bb = y[1]; y[0] = a * c4.x - bb * s4.x; y[1] = a * s4.x + bb * c4.x;
                    a = y[2]; bb = y[3]; y[2] = a * c4.y - bb * s4.y; y[3] = a * s4.y + bb * c4.y;
                    a = y[4]; bb = y[5]; y[4] = a * c4.z - bb * s4.z; y[5] = a * s4.z + bb * c4.z;
                    a = y[6]; bb = y[7]; y[6] = a * c4.w - bb * s4.w; y[7] = a * s4.w + bb * c4.w;
                }
                bf16x8 o;
                #pragma unroll
                for (int e = 0; e < 8; e++) o[e] = f2bf(y[e] * 0.0625f);
                qf[dc] = o;
            }
        }

        if (f == nt - 1) { asm volatile("s_waitcnt vmcnt(0)" ::: "memory"); }
        else             { asm volatile("s_waitcnt vmcnt(8)" ::: "memory"); }
        __builtin_amdgcn_s_barrier();

        const int kb = 64 * (inB ? (f - nphA) : f);
        const int k0 = kb + 32 * p;
        const bool act = (k0 <= q0 + 31);
        if (act) {
            const char* Ks = (const char*)smem + (f & 1) * 65536 + p * 16384;
            const char* Vs = (const char*)smem + (f & 1) * 65536 + 32768;
            // ---- QK^T (swapped): s = K * Q; 2 chains ----
            f32x16 sA, sB;
            #pragma unroll
            for (int r = 0; r < 16; r++) { sA[r] = 0.f; sB[r] = 0.f; }
            __builtin_amdgcn_s_setprio(1);
            #pragma unroll
            for (int dc = 0; dc < 16; dc += 2) {
                int kb0 = (dc * 32 + hi * 16) ^ ((ln & 7) << 4);
                int kb1 = ((dc + 1) * 32 + hi * 16) ^ ((ln & 7) << 4);
                bf16x8 kf0 = *(const bf16x8*)(Ks + ln * 512 + kb0);
                bf16x8 kf1 = *(const bf16x8*)(Ks + ln * 512 + kb1);
                sA = __builtin_amdgcn_mfma_f32_32x32x16_bf16(kf0, qf[dc],     sA, 0, 0, 0);
                sB = __builtin_amdgcn_mfma_f32_32x32x16_bf16(kf1, qf[dc + 1], sB, 0, 0, 0);
            }
            __builtin_amdgcn_s_setprio(0);
            f32x16 s;
            #pragma unroll
            for (int r = 0; r < 16; r++) s[r] = sA[r] + sB[r];

            // ---- mask + online softmax, in-register ----
            if (k0 + 31 > q0) {
                #pragma unroll
                for (int r = 0; r < 16; r++) {
                    int key_g = k0 + (r & 3) + 8 * (r >> 2) + 4 * hi;
                    if (key_g > qg) s[r] = -1e30f;
                }
            }
            float mt = s[0];
            #pragma unroll
            for (int r = 1; r < 16; r++) mt = fmaxf(mt, s[r]);
            mt = fmaxf(mt, __shfl_xor(mt, 32));
            float mn = m;
            if (!__all(mt <= m + 8.f)) {           // defer-max (T13)
                mn = fmaxf(m, mt);
                float fe = __expf(m - mn);
                m = mn;
                float fr[16];
                #pragma unroll
                for (int r = 0; r < 16; r++)
                    fr[r] = bperm((r & 3) + 8 * (r >> 2) + 4 * hi, fe);
                #pragma unroll
                for (int i = 0; i < 8; i++)
                    #pragma unroll
                    for (int r = 0; r < 16; r++) acc[i][r] *= fr[r];
                l *= fe;
            }
            float pr[16], ps = 0.f;
            #pragma unroll
            for (int r = 0; r < 16; r++) { pr[r] = __expf(s[r] - mn); ps += pr[r]; }
            ps += __shfl_xor(ps, 32);
            l += ps;

            // ---- P -> bf16 A-frags (T12) ----
            unsigned pw[8];
            #pragma unroll
            for (int kc = 0; kc < 2; kc++) {
                unsigned X = cvtpk(pr[kc * 8 + 0], pr[kc * 8 + 1]);
                unsigned Y = cvtpk(pr[kc * 8 + 4], pr[kc * 8 + 5]);
                unsigned Z = cvtpk(pr[kc * 8 + 2], pr[kc * 8 + 3]);
                unsigned W = cvtpk(pr[kc * 8 + 6], pr[kc * 8 + 7]);
                asm volatile("v_permlane32_swap_b32 %0, %1" : "+v"(X), "+v"(Y));
                asm volatile("v_permlane32_swap_b32 %0, %1" : "+v"(Z), "+v"(W));
                pw[kc * 4 + 0] = X; pw[kc * 4 + 1] = Z;
                pw[kc * 4 + 2] = Y; pw[kc * 4 + 3] = W;
            }
            u32x4 w0v = {pw[0], pw[1], pw[2], pw[3]};
            u32x4 w1v = {pw[4], pw[5], pw[6], pw[7]};
            bf16x8 pa0 = __builtin_bit_cast(bf16x8, w0v);
            bf16x8 pa1 = __builtin_bit_cast(bf16x8, w1v);

            // ---- PV over this wave's 32 keys (parity half of 128B V rows) --
            __builtin_amdgcn_s_setprio(1);
            #pragma unroll
            for (int db = 0; db < 8; db++) {
                int drow = db * 32 + ln;
                int sw = (drow & 7) << 4;
                bf16x8 vf0 = *(const bf16x8*)(Vs + drow * 128 + ((p * 64 + hi * 16) ^ sw));
                bf16x8 vf1 = *(const bf16x8*)(Vs + drow * 128 + ((p * 64 + 32 + hi * 16) ^ sw));
                acc[db] = __builtin_amdgcn_mfma_f32_32x32x16_bf16(pa0, vf0, acc[db], 0, 0, 0);
                acc[db] = __builtin_amdgcn_mfma_f32_32x32x16_bf16(pa1, vf1, acc[db], 0, 0, 0);
            }
            __builtin_amdgcn_s_setprio(0);
        }
        __builtin_amdgcn_s_barrier();
        if (f + 2 < nt) {
            int f2 = f + 2;
            int kb2 = 64 * ((f2 >= nphA) ? (f2 - nphA) : f2);
            stage_kv(Kb, Vb, smem, f & 1, kb2, w, lane);
        }
        __builtin_amdgcn_sched_barrier(0);

        // ---- chunk end: parity merge + store (inline, appears once) ----
        if (f == nphA - 1 || f == nt - 1) {
            float* accb = (float*)(smem + 131072);
            float* mlb  = (float*)(smem + 147456);
            float fr0[16], fr1[16];
            for (int gr = 0; gr < 4; gr++) {
                MERGE_HALF(0)
                MERGE_HALF(1)
            }
        }
    }
}

extern "C" void kernel_launch(void* const* d_in, const int* in_sizes, int n_in,
                              void* d_out, int out_size, void* d_ws, size_t ws_size,
                              hipStream_t stream) {
    const float* x    = (const float*)d_in[0];
    const float* cosb = (const float*)d_in[1];
    const float* sinb = (const float*)d_in[2];
    // d_in[3] = mask: equivalent to causal; computed analytically in-kernel
    const float* wq   = (const float*)d_in[4];
    const float* wk   = (const float*)d_in[5];
    const float* wv   = (const float*)d_in[6];
    const float* wo   = (const float*)d_in[7];
    const float* qnw  = (const float*)d_in[8];
    const float* knw  = (const float*)d_in[9];
    float* out = (float*)d_out;

    char* ws = (char*)d_ws;
    short* xb   = (short*)(ws + 0);          // 4096x512 bf16               [0, 4194304)
    short* wfus = (short*)(ws + 4194304);    // [3072][512] wq|wk|wv^T      [4194304, 7340032)
    short* wot  = (short*)(ws + 7340032);    // [512][2048] wo^T            [7340032, 9437184)
    short* C    = (short*)(ws + 9437184);    // 4096x3072 fused QKV out     [9437184, 34603008)
    short* ao   = (short*)(ws + 34603008);   // flash out (C stays live: Q source)
    short* kr   = (short*)(ws + 51380224);   // [b][kv][s][d] 4 MB          [51380224, 55574528)
    short* vr   = (short*)(ws + 55574528);   // [b][kv][d][s] 4 MB          [55574528, 59768832)

    cvt_kernel<<<2048, 256, 0, stream>>>(x, xb, 2097152);
    wt_kernel<<<dim3(32, 8), 256, 0, stream>>>(wq, wfus,              512, 2048);
    wt_kernel<<<dim3(8, 8),  256, 0, stream>>>(wk, wfus + 2048 * 512, 512, 512);
    wt_kernel<<<dim3(8, 8),  256, 0, stream>>>(wv, wfus + 2560 * 512, 512, 512);
    wt_kernel<<<dim3(8, 32), 256, 0, stream>>>(wo, wot, 2048, 512);

    // fused QKV projection: C[4096][3072]
    gemm_bt<128, 1><<<dim3(24, 32), 256, 0, stream>>>(xb, wfus, C, 4096, 3072, 512);

    // K norm+rope -> kr ; V transpose -> vr (Q norm+rope fused into flash)
    norm_rope_kernel<<<2048, 256, 0, stream>>>(C, kr, knw, cosb, sinb, 2,
                                               3072L, 2048L, 1048576L, 524288L, 256L, 1.0f);
    transpose_v_kernel<<<dim3(32, 4, 4), 256, 0, stream>>>(C, vr);

    flash_kernel<<<256, 512, 0, stream>>>(C, kr, vr, ao, qnw, cosb, sinb);

    gemm_bt<64, 0><<<dim3(8, 32), 256, 0, stream>>>(ao, wot, out, 4096, 512, 2048);
}

// Round 13
// 276.806 us; speedup vs baseline: 3.6321x; 1.8015x over previous
//
#include <hip/hip_runtime.h>

#define S_LEN 2048
#define NHQ 8
#define NKV 2
#define HD 256
#define KVB 32

typedef __attribute__((ext_vector_type(8))) short bf16x8;
typedef __attribute__((ext_vector_type(4))) short bf16x4;
typedef __attribute__((ext_vector_type(4))) float f32x4;
typedef __attribute__((ext_vector_type(16))) float f32x16;
typedef __attribute__((ext_vector_type(4))) unsigned u32x4;

__device__ __forceinline__ short f2bf(float f) {
    unsigned u = __builtin_bit_cast(unsigned, f);
    u += 0x7FFFu + ((u >> 16) & 1u);
    return (short)(u >> 16);
}
__device__ __forceinline__ float bf2f(short s) {
    unsigned u = ((unsigned)(unsigned short)s) << 16;
    return __builtin_bit_cast(float, u);
}
__device__ __forceinline__ unsigned cvtpk(float a, float b) {
    unsigned r;
    asm("v_cvt_pk_bf16_f32 %0, %1, %2" : "=v"(r) : "v"(a), "v"(b));
    return r;
}
__device__ __forceinline__ void gload16(const short* g, short* l) {
    __builtin_amdgcn_global_load_lds((const __attribute__((address_space(1))) unsigned*)g,
                                     (__attribute__((address_space(3))) unsigned*)l, 16, 0, 0);
}
__device__ __forceinline__ float bperm(int srclane, float v) {
    return __builtin_bit_cast(float,
        __builtin_amdgcn_ds_bpermute(srclane * 4, __builtin_bit_cast(int, v)));
}

// ---------------- fp32 -> bf16 convert ----------------
__global__ __launch_bounds__(256) void cvt_kernel(const float* __restrict__ in,
                                                  short* __restrict__ out, int n) {
    int i = (blockIdx.x * 256 + threadIdx.x) * 4;
    if (i + 3 < n) {
        float4 f = *(const float4*)(in + i);
        bf16x4 o;
        o[0] = f2bf(f.x); o[1] = f2bf(f.y); o[2] = f2bf(f.z); o[3] = f2bf(f.w);
        *(bf16x4*)(out + i) = o;
    }
}

// ---------------- fp32 W[K][N] -> bf16 Wt[N][K] (convert + transpose) -------
__global__ __launch_bounds__(256) void wt_kernel(const float* __restrict__ in,
                                                 short* __restrict__ out,
                                                 int K, int N) {
    __shared__ short tile[64][72];
    int n0 = blockIdx.x * 64, k0 = blockIdx.y * 64;
    int t = threadIdx.x;
    #pragma unroll
    for (int i = 0; i < 16; i++) {
        int flat = i * 256 + t; int r = flat >> 6, c = flat & 63;
        tile[r][c] = f2bf(in[(long)(k0 + r) * N + n0 + c]);
    }
    __syncthreads();
    #pragma unroll
    for (int i = 0; i < 16; i++) {
        int flat = i * 256 + t; int r = flat >> 6, c = flat & 63;
        out[(long)(n0 + r) * K + k0 + c] = tile[c][r];
    }
}

// ---------------- m97-style GEMM: C[M][N] = A[M][K] @ Bt[N][K]^T ------------
template<int BN, int WRITE_BF16>
__global__ __launch_bounds__(256) void gemm_bt(const short* __restrict__ A,
                                               const short* __restrict__ Bt,
                                               void* __restrict__ Cv,
                                               int M, int N, int K) {
    constexpr int NI = BN / 32;          // B-frags per wave
    __shared__ short As[128 * 32];
    __shared__ short Bs[BN * 32];
    const int t = threadIdx.x;
    const int lane = t & 63, w = t >> 6;
    const int lr = lane & 15, lg = lane >> 4;
    const int m0 = blockIdx.y * 128, n0 = blockIdx.x * BN;
    const int wm = (w >> 1) * 64, wn = (w & 1) * (BN / 2);

    f32x4 acc[4][NI];
    #pragma unroll
    for (int i = 0; i < 4; i++)
        #pragma unroll
        for (int j = 0; j < NI; j++) acc[i][j] = (f32x4){0.f, 0.f, 0.f, 0.f};

    for (int k0 = 0; k0 < K; k0 += 32) {
        __syncthreads();
        #pragma unroll
        for (int r = 0; r < 2; r++) {            // A tile: 128x32 = 8 KB
            int sbase = r * 2048 + w * 512;
            int srow = (sbase + lane * 8) >> 5, scol = (sbase + lane * 8) & 31;
            gload16(A + (long)(m0 + srow) * K + k0 + scol, &As[sbase]);
        }
        #pragma unroll
        for (int r = 0; r < BN / 64; r++) {      // B tile: BNx32
            int sbase = r * 2048 + w * 512;
            int srow = (sbase + lane * 8) >> 5, scol = (sbase + lane * 8) & 31;
            gload16(Bt + (long)(n0 + srow) * K + k0 + scol, &Bs[sbase]);
        }
        __syncthreads();
        bf16x8 af[4], bfr[NI];
        #pragma unroll
        for (int mi = 0; mi < 4; mi++)
            af[mi] = *(const bf16x8*)&As[(wm + mi * 16 + lr) * 32 + lg * 8];
        #pragma unroll
        for (int ni = 0; ni < NI; ni++)
            bfr[ni] = *(const bf16x8*)&Bs[(wn + ni * 16 + lr) * 32 + lg * 8];
        #pragma unroll
        for (int mi = 0; mi < 4; mi++)
            #pragma unroll
            for (int ni = 0; ni < NI; ni++)
                acc[mi][ni] = __builtin_amdgcn_mfma_f32_16x16x32_bf16(af[mi], bfr[ni], acc[mi][ni], 0, 0, 0);
    }
    #pragma unroll
    for (int mi = 0; mi < 4; mi++)
    #pragma unroll
    for (int ni = 0; ni < NI; ni++)
    #pragma unroll
    for (int r = 0; r < 4; r++) {
        long row = m0 + wm + mi * 16 + lg * 4 + r;
        long col = n0 + wn + ni * 16 + lr;
        float v = acc[mi][ni][r];
        if (WRITE_BF16) ((short*)Cv)[row * N + col] = f2bf(v);
        else            ((float*)Cv)[row * N + col] = v;
    }
}

// ---------------- RMSNorm + partial RoPE (K path) ---------------------------
__global__ __launch_bounds__(256) void norm_rope_kernel(
    const short* __restrict__ in, short* __restrict__ out,
    const float* __restrict__ w, const float* __restrict__ cosb,
    const float* __restrict__ sinb, int H, long ldin, long cofs,
    long ob, long oh, long os, float scale) {
    int vec = blockIdx.x * 4 + (threadIdx.x >> 6);
    int lane = threadIdx.x & 63;
    int token = vec / H, head = vec % H;
    int b = token / S_LEN, s = token % S_LEN;

    bf16x4 xv = *(const bf16x4*)(in + (long)token * ldin + cofs + head * 256 + lane * 4);
    float x0 = bf2f(xv[0]), x1 = bf2f(xv[1]), x2 = bf2f(xv[2]), x3 = bf2f(xv[3]);
    float ss = x0 * x0 + x1 * x1 + x2 * x2 + x3 * x3;
    #pragma unroll
    for (int m = 1; m < 64; m <<= 1) ss += __shfl_xor(ss, m);
    float inv = rsqrtf(ss * (1.f / 256.f) + 1e-6f);

    float4 wv = *(const float4*)(w + lane * 4);
    float y0 = x0 * inv * (1.f + wv.x);
    float y1 = x1 * inv * (1.f + wv.y);
    float y2 = x2 * inv * (1.f + wv.z);
    float y3 = x3 * inv * (1.f + wv.w);

    if (lane < 16) {
        float2 c = *(const float2*)&cosb[s * 32 + lane * 2];
        float2 sn = *(const float2*)&sinb[s * 32 + lane * 2];
        float a0 = y0 * c.x - y1 * sn.x, b0 = y0 * sn.x + y1 * c.x;
        float a1 = y2 * c.y - y3 * sn.y, b1 = y2 * sn.y + y3 * c.y;
        y0 = a0; y1 = b0; y2 = a1; y3 = b1;
    }
    y0 *= scale; y1 *= scale; y2 *= scale; y3 *= scale;
    long oidx = (long)b * ob + (long)head * oh + (long)s * os + lane * 4;
    bf16x4 o; o[0] = f2bf(y0); o[1] = f2bf(y1); o[2] = f2bf(y2); o[3] = f2bf(y3);
    *(bf16x4*)(out + oidx) = o;
}

// ---------------- V transpose: C[token][2560+kv*256+d] -> vr[b][kv][d][s] ---
__global__ __launch_bounds__(256) void transpose_v_kernel(const short* __restrict__ C,
                                                          short* __restrict__ vr) {
    __shared__ short tile[64][65];
    int s0 = blockIdx.x * 64, d0 = blockIdx.y * 64;
    int bkv = blockIdx.z; int b = bkv >> 1, kv = bkv & 1;
    int t = threadIdx.x;
    #pragma unroll
    for (int i = 0; i < 16; i++) {
        int flat = i * 256 + t; int si = flat >> 6, di = flat & 63;
        tile[si][di] = C[(long)(b * S_LEN + s0 + si) * 3072 + 2560 + kv * 256 + d0 + di];
    }
    __syncthreads();
    #pragma unroll
    for (int i = 0; i < 16; i++) {
        int flat = i * 256 + t; int di = flat >> 6, si = flat & 63;
        vr[(long)(bkv * 256 + d0 + di) * S_LEN + s0 + si] = tile[si][di];
    }
}

// ---------------- flash attention: r8 skeleton + balanced pairing + Q-fusion
// 4 waves (2 q-groups x 2 key parities), 64 q rows/block, 2 blocks/CU.
// Phase: vmcnt(0)|BAR|compute|BAR|stage(ph+1). Q-prep BEFORE loop, merge AFTER
// (any in-loop state reset spills acc to scratch -- r10-r12 lesson).
// Blocks c and c+256 share a CU with j summing to 31 -> 33 phases per CU.
__global__ __launch_bounds__(256, 2) void flash_kernel(const short* __restrict__ Cq,
                                                       const short* __restrict__ Kt,
                                                       const short* __restrict__ Vt,
                                                       short* __restrict__ O,
                                                       const float* __restrict__ qnw,
                                                       const float* __restrict__ cosb,
                                                       const float* __restrict__ sinb) {
    // [0,32K): K tiles (parity p at p*16KB); [32K,64K): V tiles; epilogue reuses
    __shared__ __align__(16) char smem[66048];

    int idx = blockIdx.x;
    int half = idx >> 8, rm = idx & 255;
    int xcd = rm & 7, slot = rm >> 3;        // consecutive blocks -> XCD round-robin
    int bh = xcd * 2 + (slot & 1);           // 2 bh per XCD -> 4MB KV in its L2
    int jj = slot >> 1;                      // 0..15
    int j  = half ? jj : (31 - jj);          // CU pair (c, c+256): j1+j2 = 31
    int h = bh & 7, b = bh >> 3;
    int kv = h >> 2;
    int t = threadIdx.x, lane = t & 63, w = t >> 6;
    int g = w >> 1, p = w & 1;               // q-group, key parity
    int ln = lane & 31, hi = lane >> 5;
    int q0 = j * 64 + g * 32;
    int qg = q0 + ln;                        // this lane's q row (score column)

    const short* Kb = Kt + (long)(b * NKV + kv) * S_LEN * HD;
    const short* Vb = Vt + (long)(b * NKV + kv) * HD * S_LEN;

    // stage tiles {2*ph2, 2*ph2+1} into parity slots 0/1 (16 loads/thread)
    auto stage = [&](int ph2) {
        #pragma unroll
        for (int pp = 0; pp < 2; pp++) {
            int k0s = (2 * ph2 + pp) * KVB;
            short* Ktile = (short*)(smem + pp * 16384);
            short* Vtile = (short*)(smem + 32768 + pp * 16384);
            #pragma unroll
            for (int c = 0; c < 4; c++) {
                int o = c * 4096 + w * 1024 + lane * 16;   // byte offset in tile
                int key = o >> 9, db = o & 511;
                gload16(Kb + (long)(k0s + key) * HD + ((db ^ ((key & 7) << 4)) >> 1),
                        Ktile + (c * 4096 + w * 1024) / 2);
                int d = o >> 6, kb = o & 63;
                gload16(Vb + (long)d * S_LEN + k0s + ((kb ^ ((d & 6) << 3)) >> 1),
                        Vtile + (c * 4096 + w * 1024) / 2);
            }
        }
    };

    stage(0);

    // ---- Q load from fused C + RMSNorm + partial RoPE + 1/16 scale ----
    bf16x8 qf[16];
    {
        const short* qrow = Cq + (long)(b * S_LEN + qg) * 3072 + h * 256 + hi * 8;
        #pragma unroll
        for (int dc = 0; dc < 16; dc++) qf[dc] = *(const bf16x8*)&qrow[dc * 16];
        float ss = 0.f;
        #pragma unroll
        for (int dc = 0; dc < 16; dc++)
            #pragma unroll
            for (int e = 0; e < 8; e++) { float v = bf2f(qf[dc][e]); ss += v * v; }
        ss += __shfl_xor(ss, 32);
        float inv = rsqrtf(ss * (1.f / 256.f) + 1e-6f);
        #pragma unroll
        for (int dc = 0; dc < 16; dc++) {
            float y[8];
            float4 w0 = *(const float4*)&qnw[dc * 16 + hi * 8];
            float4 w1 = *(const float4*)&qnw[dc * 16 + hi * 8 + 4];
            y[0] = bf2f(qf[dc][0]) * inv * (1.f + w0.x);
            y[1] = bf2f(qf[dc][1]) * inv * (1.f + w0.y);
            y[2] = bf2f(qf[dc][2]) * inv * (1.f + w0.z);
            y[3] = bf2f(qf[dc][3]) * inv * (1.f + w0.w);
            y[4] = bf2f(qf[dc][4]) * inv * (1.f + w1.x);
            y[5] = bf2f(qf[dc][5]) * inv * (1.f + w1.y);
            y[6] = bf2f(qf[dc][6]) * inv * (1.f + w1.z);
            y[7] = bf2f(qf[dc][7]) * inv * (1.f + w1.w);
            if (dc < 4) {   // d < 64: rope pairs (2i,2i+1), angle idx d/2
                float4 c4 = *(const float4*)&cosb[qg * 32 + dc * 8 + hi * 4];
                float4 s4 = *(const float4*)&sinb[qg * 32 + dc * 8 + hi * 4];
                float a, bb;
                a = y[0]; bb = y[1]; y[0] = a * c4.x - bb * s4.x; y[1] = a * s4.x + bb * c4.x;
                a = y[2]; bb = y[3]; y[2] = a * c4.y - bb * s4.y; y[3] = a * s4.y + bb * c4.y;
                a = y[4]; bb = y[5]; y[4] = a * c4.z - bb * s4.z; y[5] = a * s4.z + bb * c4.z;
                a = y[6]; bb = y[7]; y[6] = a * c4.w - bb * s4.w; y[7] = a * s4.w + bb * c4.w;
            }
            bf16x8 o;
            #pragma unroll
            for (int e = 0; e < 8; e++) o[e] = f2bf(y[e] * 0.0625f);
            qf[dc] = o;
        }
    }

    f32x16 acc[8];
    #pragma unroll
    for (int i = 0; i < 8; i++)
        #pragma unroll
        for (int jj2 = 0; jj2 < 16; jj2++) acc[i][jj2] = 0.f;
    float m = -1e30f, l = 0.f;

    auto compute = [&](int k0) {
        const char* Ks = (const char*)smem + p * 16384;
        const char* Vs = (const char*)smem + 32768 + p * 16384;
        // ---- QK^T (swapped): s = K * Q, D[key][q]; 2 chains ----
        f32x16 sA, sB;
        #pragma unroll
        for (int r = 0; r < 16; r++) { sA[r] = 0.f; sB[r] = 0.f; }
        __builtin_amdgcn_s_setprio(1);
        #pragma unroll
        for (int dc = 0; dc < 16; dc += 2) {
            int kb0 = (dc * 32 + hi * 16) ^ ((ln & 7) << 4);
            int kb1 = ((dc + 1) * 32 + hi * 16) ^ ((ln & 7) << 4);
            bf16x8 kf0 = *(const bf16x8*)(Ks + ln * 512 + kb0);
            bf16x8 kf1 = *(const bf16x8*)(Ks + ln * 512 + kb1);
            sA = __builtin_amdgcn_mfma_f32_32x32x16_bf16(kf0, qf[dc],     sA, 0, 0, 0);
            sB = __builtin_amdgcn_mfma_f32_32x32x16_bf16(kf1, qf[dc + 1], sB, 0, 0, 0);
        }
        __builtin_amdgcn_s_setprio(0);
        f32x16 s;
        #pragma unroll
        for (int r = 0; r < 16; r++) s[r] = sA[r] + sB[r];

        // ---- mask + online softmax, fully in-register ----
        if (k0 + KVB - 1 > q0) {
            #pragma unroll
            for (int r = 0; r < 16; r++) {
                int key_g = k0 + (r & 3) + 8 * (r >> 2) + 4 * hi;
                if (key_g > qg) s[r] = -1e30f;
            }
        }
        float mt = s[0];
        #pragma unroll
        for (int r = 1; r < 16; r++) mt = fmaxf(mt, s[r]);
        mt = fmaxf(mt, __shfl_xor(mt, 32));
        float mn = m;
        if (!__all(mt <= m + 8.f)) {           // defer-max (T13)
            mn = fmaxf(m, mt);
            float f = __expf(m - mn);
            m = mn;
            float fr[16];
            #pragma unroll
            for (int r = 0; r < 16; r++)
                fr[r] = bperm((r & 3) + 8 * (r >> 2) + 4 * hi, f);
            #pragma unroll
            for (int i = 0; i < 8; i++)
                #pragma unroll
                for (int r = 0; r < 16; r++) acc[i][r] *= fr[r];
            l *= f;
        }
        float pr[16], ps = 0.f;
        #pragma unroll
        for (int r = 0; r < 16; r++) { pr[r] = __expf(s[r] - mn); ps += pr[r]; }
        ps += __shfl_xor(ps, 32);
        l += ps;

        // ---- P -> bf16 A-fragments via cvt_pk + permlane32_swap (T12) ----
        unsigned pw[8];
        #pragma unroll
        for (int kc = 0; kc < 2; kc++) {
            unsigned X = cvtpk(pr[kc * 8 + 0], pr[kc * 8 + 1]);
            unsigned Y = cvtpk(pr[kc * 8 + 4], pr[kc * 8 + 5]);
            unsigned Z = cvtpk(pr[kc * 8 + 2], pr[kc * 8 + 3]);
            unsigned W = cvtpk(pr[kc * 8 + 6], pr[kc * 8 + 7]);
            asm volatile("v_permlane32_swap_b32 %0, %1" : "+v"(X), "+v"(Y));
            asm volatile("v_permlane32_swap_b32 %0, %1" : "+v"(Z), "+v"(W));
            pw[kc * 4 + 0] = X; pw[kc * 4 + 1] = Z;
            pw[kc * 4 + 2] = Y; pw[kc * 4 + 3] = W;
        }
        u32x4 w0v = {pw[0], pw[1], pw[2], pw[3]};
        u32x4 w1v = {pw[4], pw[5], pw[6], pw[7]};
        bf16x8 pa0 = __builtin_bit_cast(bf16x8, w0v);
        bf16x8 pa1 = __builtin_bit_cast(bf16x8, w1v);

        // ---- PV: acc[db] += P * V, D[q][d], lane owns d column ----
        __builtin_amdgcn_s_setprio(1);
        #pragma unroll
        for (int db = 0; db < 8; db++) {
            int drow = db * 32 + ln;
            int sw = (drow & 6) << 3;
            bf16x8 vf0 = *(const bf16x8*)(Vs + drow * 64 + ((hi * 16) ^ sw));
            bf16x8 vf1 = *(const bf16x8*)(Vs + drow * 64 + ((32 + hi * 16) ^ sw));
            acc[db] = __builtin_amdgcn_mfma_f32_32x32x16_bf16(pa0, vf0, acc[db], 0, 0, 0);
            acc[db] = __builtin_amdgcn_mfma_f32_32x32x16_bf16(pa1, vf1, acc[db], 0, 0, 0);
        }
        __builtin_amdgcn_s_setprio(0);
    };

    for (int ph = 0; ph <= j; ph++) {
        asm volatile("s_waitcnt vmcnt(0)" ::: "memory");
        __builtin_amdgcn_s_barrier();
        int k0 = (2 * ph + p) * KVB;
        if (k0 <= q0 + 31) compute(k0);      // skip only fully-masked diagonal tile
        __builtin_amdgcn_s_barrier();
        if (ph < j) stage(ph + 1);
        __builtin_amdgcn_sched_barrier(0);
    }

    // ---- parity merge epilogue (staging LDS is dead) ----
    float* accb = (float*)smem;                 // [g][128][64] f32
    float* mlb  = (float*)(smem + 65536);       // m: [0,64), l: [64,128)
    if (p == 1) {
        #pragma unroll
        for (int db = 0; db < 8; db++)
            #pragma unroll
            for (int r = 0; r < 16; r++)
                accb[g * 8192 + (db * 16 + r) * 64 + hi * 32 + ln] = acc[db][r];
        if (hi == 0) { mlb[g * 32 + ln] = m; mlb[64 + g * 32 + ln] = l; }
    }
    __syncthreads();
    if (p == 0) {
        float m1 = mlb[g * 32 + ln], l1 = mlb[64 + g * 32 + ln];
        float M  = fmaxf(m, m1);
        float f0 = __expf(m - M), f1 = __expf(m1 - M);
        float lt = l * f0 + l1 * f1;
        float w0 = f0 / lt, w1 = f1 / lt;
        float fr0[16], fr1[16];
        #pragma unroll
        for (int r = 0; r < 16; r++) {
            int crow = (r & 3) + 8 * (r >> 2) + 4 * hi;
            fr0[r] = bperm(crow, w0);
            fr1[r] = bperm(crow, w1);
        }
        #pragma unroll
        for (int db = 0; db < 8; db++)
            #pragma unroll
            for (int r = 0; r < 16; r++) {
                float a1 = accb[g * 8192 + (db * 16 + r) * 64 + hi * 32 + ln];
                int qrow = q0 + (r & 3) + 8 * (r >> 2) + 4 * hi;
                O[(long)(b * S_LEN + qrow) * 2048 + h * HD + db * 32 + ln] =
                    f2bf(acc[db][r] * fr0[r] + a1 * fr1[r]);
            }
    }
}

extern "C" void kernel_launch(void* const* d_in, const int* in_sizes, int n_in,
                              void* d_out, int out_size, void* d_ws, size_t ws_size,
                              hipStream_t stream) {
    const float* x    = (const float*)d_in[0];
    const float* cosb = (const float*)d_in[1];
    const float* sinb = (const float*)d_in[2];
    // d_in[3] = mask: equivalent to causal; computed analytically in-kernel
    const float* wq   = (const float*)d_in[4];
    const float* wk   = (const float*)d_in[5];
    const float* wv   = (const float*)d_in[6];
    const float* wo   = (const float*)d_in[7];
    const float* qnw  = (const float*)d_in[8];
    const float* knw  = (const float*)d_in[9];
    float* out = (float*)d_out;

    char* ws = (char*)d_ws;
    short* xb   = (short*)(ws + 0);          // 4096x512 bf16               [0, 4194304)
    short* wfus = (short*)(ws + 4194304);    // [3072][512] wq|wk|wv^T      [4194304, 7340032)
    short* wot  = (short*)(ws + 7340032);    // [512][2048] wo^T            [7340032, 9437184)
    short* C    = (short*)(ws + 9437184);    // 4096x3072 fused QKV out     [9437184, 34603008)
    short* ao   = (short*)(ws + 34603008);   // flash out (C stays live: Q source)
    short* kr   = (short*)(ws + 51380224);   // [b][kv][s][d] 4 MB          [51380224, 55574528)
    short* vr   = (short*)(ws + 55574528);   // [b][kv][d][s] 4 MB          [55574528, 59768832)

    cvt_kernel<<<2048, 256, 0, stream>>>(x, xb, 2097152);
    wt_kernel<<<dim3(32, 8), 256, 0, stream>>>(wq, wfus,              512, 2048);
    wt_kernel<<<dim3(8, 8),  256, 0, stream>>>(wk, wfus + 2048 * 512, 512, 512);
    wt_kernel<<<dim3(8, 8),  256, 0, stream>>>(wv, wfus + 2560 * 512, 512, 512);
    wt_kernel<<<dim3(8, 32), 256, 0, stream>>>(wo, wot, 2048, 512);

    // fused QKV projection: C[4096][3072]
    gemm_bt<128, 1><<<dim3(24, 32), 256, 0, stream>>>(xb, wfus, C, 4096, 3072, 512);

    // K norm+rope -> kr ; V transpose -> vr (Q norm+rope fused into flash)
    norm_rope_kernel<<<2048, 256, 0, stream>>>(C, kr, knw, cosb, sinb, 2,
                                               3072L, 2048L, 1048576L, 524288L, 256L, 1.0f);
    transpose_v_kernel<<<dim3(32, 4, 4), 256, 0, stream>>>(C, vr);

    flash_kernel<<<512, 256, 0, stream>>>(C, kr, vr, ao, qnw, cosb, sinb);

    gemm_bt<64, 0><<<dim3(8, 32), 256, 0, stream>>>(ao, wot, out, 4096, 512, 2048);
}

// Round 14
// 208.261 us; speedup vs baseline: 4.8275x; 1.3291x over previous
//
#include <hip/hip_runtime.h>

#define S_LEN 2048
#define NHQ 8
#define NKV 2
#define HD 256
#define KVB 32

typedef __attribute__((ext_vector_type(8))) short bf16x8;
typedef __attribute__((ext_vector_type(4))) short bf16x4;
typedef __attribute__((ext_vector_type(4))) float f32x4;
typedef __attribute__((ext_vector_type(16))) float f32x16;
typedef __attribute__((ext_vector_type(4))) unsigned u32x4;

__device__ __forceinline__ short f2bf(float f) {
    unsigned u = __builtin_bit_cast(unsigned, f);
    u += 0x7FFFu + ((u >> 16) & 1u);
    return (short)(u >> 16);
}
__device__ __forceinline__ float bf2f(short s) {
    unsigned u = ((unsigned)(unsigned short)s) << 16;
    return __builtin_bit_cast(float, u);
}
__device__ __forceinline__ unsigned cvtpk(float a, float b) {
    unsigned r;
    asm("v_cvt_pk_bf16_f32 %0, %1, %2" : "=v"(r) : "v"(a), "v"(b));
    return r;
}
__device__ __forceinline__ void gload16(const short* g, short* l) {
    __builtin_amdgcn_global_load_lds((const __attribute__((address_space(1))) unsigned*)g,
                                     (__attribute__((address_space(3))) unsigned*)l, 16, 0, 0);
}
__device__ __forceinline__ float bperm(int srclane, float v) {
    return __builtin_bit_cast(float,
        __builtin_amdgcn_ds_bpermute(srclane * 4, __builtin_bit_cast(int, v)));
}

// ---------------- fp32 -> bf16 convert ----------------
__global__ __launch_bounds__(256) void cvt_kernel(const float* __restrict__ in,
                                                  short* __restrict__ out, int n) {
    int i = (blockIdx.x * 256 + threadIdx.x) * 4;
    if (i + 3 < n) {
        float4 f = *(const float4*)(in + i);
        bf16x4 o;
        o[0] = f2bf(f.x); o[1] = f2bf(f.y); o[2] = f2bf(f.z); o[3] = f2bf(f.w);
        *(bf16x4*)(out + i) = o;
    }
}

// ---------------- fp32 W[K][N] -> bf16 Wt[N][K] (convert + transpose) -------
__global__ __launch_bounds__(256) void wt_kernel(const float* __restrict__ in,
                                                 short* __restrict__ out,
                                                 int K, int N) {
    __shared__ short tile[64][72];
    int n0 = blockIdx.x * 64, k0 = blockIdx.y * 64;
    int t = threadIdx.x;
    #pragma unroll
    for (int i = 0; i < 16; i++) {
        int flat = i * 256 + t; int r = flat >> 6, c = flat & 63;
        tile[r][c] = f2bf(in[(long)(k0 + r) * N + n0 + c]);
    }
    __syncthreads();
    #pragma unroll
    for (int i = 0; i < 16; i++) {
        int flat = i * 256 + t; int r = flat >> 6, c = flat & 63;
        out[(long)(n0 + r) * K + k0 + c] = tile[c][r];
    }
}

// ---------------- m97-style GEMM: C[M][N] = A[M][K] @ Bt[N][K]^T ------------
template<int BN, int WRITE_BF16>
__global__ __launch_bounds__(256) void gemm_bt(const short* __restrict__ A,
                                               const short* __restrict__ Bt,
                                               void* __restrict__ Cv,
                                               int M, int N, int K) {
    constexpr int NI = BN / 32;          // B-frags per wave
    __shared__ short As[128 * 32];
    __shared__ short Bs[BN * 32];
    const int t = threadIdx.x;
    const int lane = t & 63, w = t >> 6;
    const int lr = lane & 15, lg = lane >> 4;
    const int m0 = blockIdx.y * 128, n0 = blockIdx.x * BN;
    const int wm = (w >> 1) * 64, wn = (w & 1) * (BN / 2);

    f32x4 acc[4][NI];
    #pragma unroll
    for (int i = 0; i < 4; i++)
        #pragma unroll
        for (int j = 0; j < NI; j++) acc[i][j] = (f32x4){0.f, 0.f, 0.f, 0.f};

    for (int k0 = 0; k0 < K; k0 += 32) {
        __syncthreads();
        #pragma unroll
        for (int r = 0; r < 2; r++) {            // A tile: 128x32 = 8 KB
            int sbase = r * 2048 + w * 512;
            int srow = (sbase + lane * 8) >> 5, scol = (sbase + lane * 8) & 31;
            gload16(A + (long)(m0 + srow) * K + k0 + scol, &As[sbase]);
        }
        #pragma unroll
        for (int r = 0; r < BN / 64; r++) {      // B tile: BNx32
            int sbase = r * 2048 + w * 512;
            int srow = (sbase + lane * 8) >> 5, scol = (sbase + lane * 8) & 31;
            gload16(Bt + (long)(n0 + srow) * K + k0 + scol, &Bs[sbase]);
        }
        __syncthreads();
        bf16x8 af[4], bfr[NI];
        #pragma unroll
        for (int mi = 0; mi < 4; mi++)
            af[mi] = *(const bf16x8*)&As[(wm + mi * 16 + lr) * 32 + lg * 8];
        #pragma unroll
        for (int ni = 0; ni < NI; ni++)
            bfr[ni] = *(const bf16x8*)&Bs[(wn + ni * 16 + lr) * 32 + lg * 8];
        #pragma unroll
        for (int mi = 0; mi < 4; mi++)
            #pragma unroll
            for (int ni = 0; ni < NI; ni++)
                acc[mi][ni] = __builtin_amdgcn_mfma_f32_16x16x32_bf16(af[mi], bfr[ni], acc[mi][ni], 0, 0, 0);
    }
    #pragma unroll
    for (int mi = 0; mi < 4; mi++)
    #pragma unroll
    for (int ni = 0; ni < NI; ni++)
    #pragma unroll
    for (int r = 0; r < 4; r++) {
        long row = m0 + wm + mi * 16 + lg * 4 + r;
        long col = n0 + wn + ni * 16 + lr;
        float v = acc[mi][ni][r];
        if (WRITE_BF16) ((short*)Cv)[row * N + col] = f2bf(v);
        else            ((float*)Cv)[row * N + col] = v;
    }
}

// ---------------- RMSNorm + partial RoPE --------------------------------
__global__ __launch_bounds__(256) void norm_rope_kernel(
    const short* __restrict__ in, short* __restrict__ out,
    const float* __restrict__ w, const float* __restrict__ cosb,
    const float* __restrict__ sinb, int H, long ldin, long cofs,
    long ob, long oh, long os, float scale) {
    int vec = blockIdx.x * 4 + (threadIdx.x >> 6);
    int lane = threadIdx.x & 63;
    int token = vec / H, head = vec % H;
    int b = token / S_LEN, s = token % S_LEN;

    bf16x4 xv = *(const bf16x4*)(in + (long)token * ldin + cofs + head * 256 + lane * 4);
    float x0 = bf2f(xv[0]), x1 = bf2f(xv[1]), x2 = bf2f(xv[2]), x3 = bf2f(xv[3]);
    float ss = x0 * x0 + x1 * x1 + x2 * x2 + x3 * x3;
    #pragma unroll
    for (int m = 1; m < 64; m <<= 1) ss += __shfl_xor(ss, m);
    float inv = rsqrtf(ss * (1.f / 256.f) + 1e-6f);

    float4 wv = *(const float4*)(w + lane * 4);
    float y0 = x0 * inv * (1.f + wv.x);
    float y1 = x1 * inv * (1.f + wv.y);
    float y2 = x2 * inv * (1.f + wv.z);
    float y3 = x3 * inv * (1.f + wv.w);

    if (lane < 16) {
        float2 c = *(const float2*)&cosb[s * 32 + lane * 2];
        float2 sn = *(const float2*)&sinb[s * 32 + lane * 2];
        float a0 = y0 * c.x - y1 * sn.x, b0 = y0 * sn.x + y1 * c.x;
        float a1 = y2 * c.y - y3 * sn.y, b1 = y2 * sn.y + y3 * c.y;
        y0 = a0; y1 = b0; y2 = a1; y3 = b1;
    }
    y0 *= scale; y1 *= scale; y2 *= scale; y3 *= scale;
    long oidx = (long)b * ob + (long)head * oh + (long)s * os + lane * 4;
    bf16x4 o; o[0] = f2bf(y0); o[1] = f2bf(y1); o[2] = f2bf(y2); o[3] = f2bf(y3);
    *(bf16x4*)(out + oidx) = o;
}

// ---------------- V transpose: C[token][2560+kv*256+d] -> vr[b][kv][d][s] ---
__global__ __launch_bounds__(256) void transpose_v_kernel(const short* __restrict__ C,
                                                          short* __restrict__ vr) {
    __shared__ short tile[64][65];
    int s0 = blockIdx.x * 64, d0 = blockIdx.y * 64;
    int bkv = blockIdx.z; int b = bkv >> 1, kv = bkv & 1;
    int t = threadIdx.x;
    #pragma unroll
    for (int i = 0; i < 16; i++) {
        int flat = i * 256 + t; int si = flat >> 6, di = flat & 63;
        tile[si][di] = C[(long)(b * S_LEN + s0 + si) * 3072 + 2560 + kv * 256 + d0 + di];
    }
    __syncthreads();
    #pragma unroll
    for (int i = 0; i < 16; i++) {
        int flat = i * 256 + t; int di = flat >> 6, si = flat & 63;
        vr[(long)(bkv * 256 + d0 + di) * S_LEN + s0 + si] = tile[si][di];
    }
}

// ---------------- flash attention: r8 skeleton + split-stage pipeline -------
// 4 waves (2 q-groups x 2 key parities), 64 q rows/block, 2 blocks/CU.
// r8 mapping (heavy-first, XCD round-robin). Q from qro (separate norm kernel).
// Per phase: vm8|BAR|QK|BAR|stageK+1|softmax|vm8|BAR|PV|BAR|stageV+1.
__global__ __launch_bounds__(256, 2) void flash_kernel(const short* __restrict__ Q,
                                                       const short* __restrict__ Kt,
                                                       const short* __restrict__ Vt,
                                                       short* __restrict__ O) {
    // [0,32K): K tiles (parity p at p*16KB); [32K,64K): V tiles; epilogue reuses
    __shared__ __align__(16) char smem[66048];

    int idx = blockIdx.x;
    int xcd = idx & 7, slot = idx >> 3;      // consecutive blocks -> XCD round-robin
    int bh = xcd * 2 + (slot & 1);           // 2 bh per XCD -> 4MB KV in its L2
    int j  = 31 - (slot >> 1);               // heavy-first (r8 mapping, measured best)
    int h = bh & 7, b = bh >> 3;
    int kv = h >> 2;
    int t = threadIdx.x, lane = t & 63, w = t >> 6;
    int g = w >> 1, p = w & 1;               // q-group, key parity
    int ln = lane & 31, hi = lane >> 5;
    int q0 = j * 64 + g * 32;
    int qg = q0 + ln;                        // this lane's q row (score column)

    const short* Kb = Kt + (long)(b * NKV + kv) * S_LEN * HD;
    const short* Vb = Vt + (long)(b * NKV + kv) * HD * S_LEN;

    // stage K pair {2*ph2, 2*ph2+1} (8 loads/thread)
    auto stageK = [&](int ph2) {
        #pragma unroll
        for (int pp = 0; pp < 2; pp++) {
            int k0s = (2 * ph2 + pp) * KVB;
            short* Ktile = (short*)(smem + pp * 16384);
            #pragma unroll
            for (int c = 0; c < 4; c++) {
                int o = c * 4096 + w * 1024 + lane * 16;
                int key = o >> 9, db = o & 511;
                gload16(Kb + (long)(k0s + key) * HD + ((db ^ ((key & 7) << 4)) >> 1),
                        Ktile + (c * 4096 + w * 1024) / 2);
            }
        }
    };
    // stage V pair (8 loads/thread)
    auto stageV = [&](int ph2) {
        #pragma unroll
        for (int pp = 0; pp < 2; pp++) {
            int k0s = (2 * ph2 + pp) * KVB;
            short* Vtile = (short*)(smem + 32768 + pp * 16384);
            #pragma unroll
            for (int c = 0; c < 4; c++) {
                int o = c * 4096 + w * 1024 + lane * 16;
                int d = o >> 6, kb = o & 63;
                gload16(Vb + (long)d * S_LEN + k0s + ((kb ^ ((d & 6) << 3)) >> 1),
                        Vtile + (c * 4096 + w * 1024) / 2);
            }
        }
    };

    stageK(0); stageV(0);

    // Q fragments in registers: Q[q=ln][dc*16 + hi*8 + e] (pre-normed/roped/scaled)
    bf16x8 qf[16];
    {
        const short* qrow = Q + ((long)(b * S_LEN + qg) * NHQ + h) * HD + hi * 8;
        #pragma unroll
        for (int dc = 0; dc < 16; dc++) qf[dc] = *(const bf16x8*)&qrow[dc * 16];
    }

    f32x16 acc[8];
    #pragma unroll
    for (int i = 0; i < 8; i++)
        #pragma unroll
        for (int r = 0; r < 16; r++) acc[i][r] = 0.f;
    float m = -1e30f, l = 0.f;

    for (int ph = 0; ph <= j; ph++) {
        const bool last = (ph == j);
        asm volatile("s_waitcnt vmcnt(8)" ::: "memory");   // K(ph) landed
        __builtin_amdgcn_s_barrier();
        int k0 = (2 * ph + p) * KVB;
        bool act = (k0 <= q0 + 31);

        // ---- QK^T (swapped): s = K * Q, D[key][q]; 2 chains ----
        f32x16 s;
        if (act) {
            const char* Ks = (const char*)smem + p * 16384;
            f32x16 sA, sB;
            #pragma unroll
            for (int r = 0; r < 16; r++) { sA[r] = 0.f; sB[r] = 0.f; }
            __builtin_amdgcn_s_setprio(1);
            #pragma unroll
            for (int dc = 0; dc < 16; dc += 2) {
                int kb0 = (dc * 32 + hi * 16) ^ ((ln & 7) << 4);
                int kb1 = ((dc + 1) * 32 + hi * 16) ^ ((ln & 7) << 4);
                bf16x8 kf0 = *(const bf16x8*)(Ks + ln * 512 + kb0);
                bf16x8 kf1 = *(const bf16x8*)(Ks + ln * 512 + kb1);
                sA = __builtin_amdgcn_mfma_f32_32x32x16_bf16(kf0, qf[dc],     sA, 0, 0, 0);
                sB = __builtin_amdgcn_mfma_f32_32x32x16_bf16(kf1, qf[dc + 1], sB, 0, 0, 0);
            }
            __builtin_amdgcn_s_setprio(0);
            #pragma unroll
            for (int r = 0; r < 16; r++) s[r] = sA[r] + sB[r];
        }
        __builtin_amdgcn_s_barrier();            // all waves done reading K
        if (!last) stageK(ph + 1);               // hidden under softmax + PV
        __builtin_amdgcn_sched_barrier(0);

        // ---- mask + online softmax + P->bf16, fully in-register ----
        bf16x8 pa0, pa1;
        if (act) {
            if (k0 + KVB - 1 > q0) {
                #pragma unroll
                for (int r = 0; r < 16; r++) {
                    int key_g = k0 + (r & 3) + 8 * (r >> 2) + 4 * hi;
                    if (key_g > qg) s[r] = -1e30f;
                }
            }
            float mt = s[0];
            #pragma unroll
            for (int r = 1; r < 16; r++) mt = fmaxf(mt, s[r]);
            mt = fmaxf(mt, __shfl_xor(mt, 32));
            float mn = m;
            if (!__all(mt <= m + 8.f)) {           // defer-max (T13)
                mn = fmaxf(m, mt);
                float f = __expf(m - mn);
                m = mn;
                float fr[16];
                #pragma unroll
                for (int r = 0; r < 16; r++)
                    fr[r] = bperm((r & 3) + 8 * (r >> 2) + 4 * hi, f);
                #pragma unroll
                for (int i = 0; i < 8; i++)
                    #pragma unroll
                    for (int r = 0; r < 16; r++) acc[i][r] *= fr[r];
                l *= f;
            }
            float pr[16], ps = 0.f;
            #pragma unroll
            for (int r = 0; r < 16; r++) { pr[r] = __expf(s[r] - mn); ps += pr[r]; }
            ps += __shfl_xor(ps, 32);
            l += ps;

            unsigned pw[8];
            #pragma unroll
            for (int kc = 0; kc < 2; kc++) {
                unsigned X = cvtpk(pr[kc * 8 + 0], pr[kc * 8 + 1]);
                unsigned Y = cvtpk(pr[kc * 8 + 4], pr[kc * 8 + 5]);
                unsigned Z = cvtpk(pr[kc * 8 + 2], pr[kc * 8 + 3]);
                unsigned W = cvtpk(pr[kc * 8 + 6], pr[kc * 8 + 7]);
                asm volatile("v_permlane32_swap_b32 %0, %1" : "+v"(X), "+v"(Y));
                asm volatile("v_permlane32_swap_b32 %0, %1" : "+v"(Z), "+v"(W));
                pw[kc * 4 + 0] = X; pw[kc * 4 + 1] = Z;
                pw[kc * 4 + 2] = Y; pw[kc * 4 + 3] = W;
            }
            u32x4 w0v = {pw[0], pw[1], pw[2], pw[3]};
            u32x4 w1v = {pw[4], pw[5], pw[6], pw[7]};
            pa0 = __builtin_bit_cast(bf16x8, w0v);
            pa1 = __builtin_bit_cast(bf16x8, w1v);
        }

        if (last) { asm volatile("s_waitcnt vmcnt(0)" ::: "memory"); }
        else      { asm volatile("s_waitcnt vmcnt(8)" ::: "memory"); }  // V(ph) landed
        __builtin_amdgcn_s_barrier();            // V writes visible to all waves

        // ---- PV: acc[db] += P * V ----
        if (act) {
            const char* Vs = (const char*)smem + 32768 + p * 16384;
            __builtin_amdgcn_s_setprio(1);
            #pragma unroll
            for (int db = 0; db < 8; db++) {
                int drow = db * 32 + ln;
                int sw = (drow & 6) << 3;
                bf16x8 vf0 = *(const bf16x8*)(Vs + drow * 64 + ((hi * 16) ^ sw));
                bf16x8 vf1 = *(const bf16x8*)(Vs + drow * 64 + ((32 + hi * 16) ^ sw));
                acc[db] = __builtin_amdgcn_mfma_f32_32x32x16_bf16(pa0, vf0, acc[db], 0, 0, 0);
                acc[db] = __builtin_amdgcn_mfma_f32_32x32x16_bf16(pa1, vf1, acc[db], 0, 0, 0);
            }
            __builtin_amdgcn_s_setprio(0);
        }
        __builtin_amdgcn_s_barrier();            // all waves done reading V
        if (!last) stageV(ph + 1);               // hidden under next QK
    }

    // ---- parity merge epilogue (staging LDS is dead) ----
    float* accb = (float*)smem;                 // [g][128][64] f32
    float* mlb  = (float*)(smem + 65536);       // m: [0,64), l: [64,128)
    if (p == 1) {
        #pragma unroll
        for (int db = 0; db < 8; db++)
            #pragma unroll
            for (int r = 0; r < 16; r++)
                accb[g * 8192 + (db * 16 + r) * 64 + hi * 32 + ln] = acc[db][r];
        if (hi == 0) { mlb[g * 32 + ln] = m; mlb[64 + g * 32 + ln] = l; }
    }
    __syncthreads();
    if (p == 0) {
        float m1 = mlb[g * 32 + ln], l1 = mlb[64 + g * 32 + ln];
        float M  = fmaxf(m, m1);
        float f0 = __expf(m - M), f1 = __expf(m1 - M);
        float lt = l * f0 + l1 * f1;
        float w0 = f0 / lt, w1 = f1 / lt;
        float fr0[16], fr1[16];
        #pragma unroll
        for (int r = 0; r < 16; r++) {
            int crow = (r & 3) + 8 * (r >> 2) + 4 * hi;
            fr0[r] = bperm(crow, w0);
            fr1[r] = bperm(crow, w1);
        }
        #pragma unroll
        for (int db = 0; db < 8; db++)
            #pragma unroll
            for (int r = 0; r < 16; r++) {
                float a1 = accb[g * 8192 + (db * 16 + r) * 64 + hi * 32 + ln];
                int qrow = q0 + (r & 3) + 8 * (r >> 2) + 4 * hi;
                O[(long)(b * S_LEN + qrow) * 2048 + h * HD + db * 32 + ln] =
                    f2bf(acc[db][r] * fr0[r] + a1 * fr1[r]);
            }
    }
}

extern "C" void kernel_launch(void* const* d_in, const int* in_sizes, int n_in,
                              void* d_out, int out_size, void* d_ws, size_t ws_size,
                              hipStream_t stream) {
    const float* x    = (const float*)d_in[0];
    const float* cosb = (const float*)d_in[1];
    const float* sinb = (const float*)d_in[2];
    // d_in[3] = mask: equivalent to causal; computed analytically in-kernel
    const float* wq   = (const float*)d_in[4];
    const float* wk   = (const float*)d_in[5];
    const float* wv   = (const float*)d_in[6];
    const float* wo   = (const float*)d_in[7];
    const float* qnw  = (const float*)d_in[8];
    const float* knw  = (const float*)d_in[9];
    float* out = (float*)d_out;

    char* ws = (char*)d_ws;
    short* xb   = (short*)(ws + 0);          // 4096x512 bf16               [0, 4194304)
    short* wfus = (short*)(ws + 4194304);    // [3072][512] wq|wk|wv^T      [4194304, 7340032)
    short* wot  = (short*)(ws + 7340032);    // [512][2048] wo^T            [7340032, 9437184)
    short* C    = (short*)(ws + 9437184);    // 4096x3072 fused QKV out     [9437184, 34603008)
    short* ao   = (short*)(ws + 9437184);    // flash out aliases C (C dead by then)
    short* qro  = (short*)(ws + 34603008);   // 4096x2048 roped Q           [34603008, 51380224)
    short* kr   = (short*)(ws + 51380224);   // [b][kv][s][d] 4 MB          [51380224, 55574528)
    short* vr   = (short*)(ws + 55574528);   // [b][kv][d][s] 4 MB          [55574528, 59768832)

    cvt_kernel<<<2048, 256, 0, stream>>>(x, xb, 2097152);
    wt_kernel<<<dim3(32, 8), 256, 0, stream>>>(wq, wfus,              512, 2048);
    wt_kernel<<<dim3(8, 8),  256, 0, stream>>>(wk, wfus + 2048 * 512, 512, 512);
    wt_kernel<<<dim3(8, 8),  256, 0, stream>>>(wv, wfus + 2560 * 512, 512, 512);
    wt_kernel<<<dim3(8, 32), 256, 0, stream>>>(wo, wot, 2048, 512);

    // fused QKV projection: C[4096][3072]
    gemm_bt<128, 1><<<dim3(24, 32), 256, 0, stream>>>(xb, wfus, C, 4096, 3072, 512);

    // Q gets the 1/sqrt(256) attention scale folded in for free
    norm_rope_kernel<<<8192, 256, 0, stream>>>(C, qro, qnw, cosb, sinb, 8,
                                               3072L, 0L, 4194304L, 256L, 2048L, 0.0625f);
    norm_rope_kernel<<<2048, 256, 0, stream>>>(C, kr, knw, cosb, sinb, 2,
                                               3072L, 2048L, 1048576L, 524288L, 256L, 1.0f);
    transpose_v_kernel<<<dim3(32, 4, 4), 256, 0, stream>>>(C, vr);

    flash_kernel<<<512, 256, 0, stream>>>(qro, kr, vr, ao);

    gemm_bt<64, 0><<<dim3(8, 32), 256, 0, stream>>>(ao, wot, out, 4096, 512, 2048);
}

// Round 15
// 190.864 us; speedup vs baseline: 5.2675x; 1.0911x over previous
//
#include <hip/hip_runtime.h>

#define S_LEN 2048
#define NHQ 8
#define NKV 2
#define HD 256
#define KVB 32

typedef __attribute__((ext_vector_type(8))) short bf16x8;
typedef __attribute__((ext_vector_type(4))) short bf16x4;
typedef __attribute__((ext_vector_type(4))) float f32x4;
typedef __attribute__((ext_vector_type(16))) float f32x16;
typedef __attribute__((ext_vector_type(4))) unsigned u32x4;

__device__ __forceinline__ short f2bf(float f) {
    unsigned u = __builtin_bit_cast(unsigned, f);
    u += 0x7FFFu + ((u >> 16) & 1u);
    return (short)(u >> 16);
}
__device__ __forceinline__ float bf2f(short s) {
    unsigned u = ((unsigned)(unsigned short)s) << 16;
    return __builtin_bit_cast(float, u);
}
__device__ __forceinline__ unsigned cvtpk(float a, float b) {
    unsigned r;
    asm("v_cvt_pk_bf16_f32 %0, %1, %2" : "=v"(r) : "v"(a), "v"(b));
    return r;
}
__device__ __forceinline__ void gload16(const short* g, short* l) {
    __builtin_amdgcn_global_load_lds((const __attribute__((address_space(1))) unsigned*)g,
                                     (__attribute__((address_space(3))) unsigned*)l, 16, 0, 0);
}
__device__ __forceinline__ float bperm(int srclane, float v) {
    return __builtin_bit_cast(float,
        __builtin_amdgcn_ds_bpermute(srclane * 4, __builtin_bit_cast(int, v)));
}

// ---------------- fp32 -> bf16 convert ----------------
__global__ __launch_bounds__(256) void cvt_kernel(const float* __restrict__ in,
                                                  short* __restrict__ out, int n) {
    int i = (blockIdx.x * 256 + threadIdx.x) * 4;
    if (i + 3 < n) {
        float4 f = *(const float4*)(in + i);
        bf16x4 o;
        o[0] = f2bf(f.x); o[1] = f2bf(f.y); o[2] = f2bf(f.z); o[3] = f2bf(f.w);
        *(bf16x4*)(out + i) = o;
    }
}

// ------- fused weight prep: all four W[K][N] -> bf16 Wt[N][K] transposes ----
// bid <256: wq(512x2048) | <320: wk(512x512) | <384: wv | <640: wo(2048x512)
__global__ __launch_bounds__(256) void wt_all_kernel(const float* __restrict__ wq,
                                                     const float* __restrict__ wk,
                                                     const float* __restrict__ wv,
                                                     const float* __restrict__ wo,
                                                     short* __restrict__ wfus,
                                                     short* __restrict__ wot) {
    __shared__ short tile[64][72];
    int bid = blockIdx.x;
    const float* in; short* out; int K, N, nx, base;
    if (bid < 256)      { in = wq; out = wfus;             K = 512;  N = 2048; nx = 32; base = 0;   }
    else if (bid < 320) { in = wk; out = wfus + 2048 * 512; K = 512;  N = 512;  nx = 8;  base = 256; }
    else if (bid < 384) { in = wv; out = wfus + 2560 * 512; K = 512;  N = 512;  nx = 8;  base = 320; }
    else                { in = wo; out = wot;              K = 2048; N = 512;  nx = 8;  base = 384; }
    int lb = bid - base;
    int n0 = (lb % nx) * 64, k0 = (lb / nx) * 64;
    int t = threadIdx.x;
    #pragma unroll
    for (int i = 0; i < 16; i++) {
        int flat = i * 256 + t; int r = flat >> 6, c = flat & 63;
        tile[r][c] = f2bf(in[(long)(k0 + r) * N + n0 + c]);
    }
    __syncthreads();
    #pragma unroll
    for (int i = 0; i < 16; i++) {
        int flat = i * 256 + t; int r = flat >> 6, c = flat & 63;
        out[(long)(n0 + r) * K + k0 + c] = tile[c][r];
    }
}

// ---------------- m97-style GEMM: C[M][N] = A[M][K] @ Bt[N][K]^T ------------
template<int BN, int WRITE_BF16>
__global__ __launch_bounds__(256) void gemm_bt(const short* __restrict__ A,
                                               const short* __restrict__ Bt,
                                               void* __restrict__ Cv,
                                               int M, int N, int K) {
    constexpr int NI = BN / 32;          // B-frags per wave
    __shared__ short As[128 * 32];
    __shared__ short Bs[BN * 32];
    const int t = threadIdx.x;
    const int lane = t & 63, w = t >> 6;
    const int lr = lane & 15, lg = lane >> 4;
    const int m0 = blockIdx.y * 128, n0 = blockIdx.x * BN;
    const int wm = (w >> 1) * 64, wn = (w & 1) * (BN / 2);

    f32x4 acc[4][NI];
    #pragma unroll
    for (int i = 0; i < 4; i++)
        #pragma unroll
        for (int j = 0; j < NI; j++) acc[i][j] = (f32x4){0.f, 0.f, 0.f, 0.f};

    for (int k0 = 0; k0 < K; k0 += 32) {
        __syncthreads();
        #pragma unroll
        for (int r = 0; r < 2; r++) {            // A tile: 128x32 = 8 KB
            int sbase = r * 2048 + w * 512;
            int srow = (sbase + lane * 8) >> 5, scol = (sbase + lane * 8) & 31;
            gload16(A + (long)(m0 + srow) * K + k0 + scol, &As[sbase]);
        }
        #pragma unroll
        for (int r = 0; r < BN / 64; r++) {      // B tile: BNx32
            int sbase = r * 2048 + w * 512;
            int srow = (sbase + lane * 8) >> 5, scol = (sbase + lane * 8) & 31;
            gload16(Bt + (long)(n0 + srow) * K + k0 + scol, &Bs[sbase]);
        }
        __syncthreads();
        bf16x8 af[4], bfr[NI];
        #pragma unroll
        for (int mi = 0; mi < 4; mi++)
            af[mi] = *(const bf16x8*)&As[(wm + mi * 16 + lr) * 32 + lg * 8];
        #pragma unroll
        for (int ni = 0; ni < NI; ni++)
            bfr[ni] = *(const bf16x8*)&Bs[(wn + ni * 16 + lr) * 32 + lg * 8];
        #pragma unroll
        for (int mi = 0; mi < 4; mi++)
            #pragma unroll
            for (int ni = 0; ni < NI; ni++)
                acc[mi][ni] = __builtin_amdgcn_mfma_f32_16x16x32_bf16(af[mi], bfr[ni], acc[mi][ni], 0, 0, 0);
    }
    #pragma unroll
    for (int mi = 0; mi < 4; mi++)
    #pragma unroll
    for (int ni = 0; ni < NI; ni++)
    #pragma unroll
    for (int r = 0; r < 4; r++) {
        long row = m0 + wm + mi * 16 + lg * 4 + r;
        long col = n0 + wn + ni * 16 + lr;
        float v = acc[mi][ni][r];
        if (WRITE_BF16) ((short*)Cv)[row * N + col] = f2bf(v);
        else            ((float*)Cv)[row * N + col] = v;
    }
}

// ------- fused RMSNorm + partial RoPE for Q and K in one launch -------------
// bid < 8192: Q (H=8, out qro, scale 1/16); else: K (H=2, out kr)
__global__ __launch_bounds__(256) void norm_rope2_kernel(
    const short* __restrict__ C, short* __restrict__ qout, short* __restrict__ kout,
    const float* __restrict__ qw, const float* __restrict__ kw,
    const float* __restrict__ cosb, const float* __restrict__ sinb) {
    int bid = blockIdx.x;
    bool isQ = bid < 8192;
    int H        = isQ ? 8 : 2;
    long cofs    = isQ ? 0L : 2048L;
    const float* w = isQ ? qw : kw;
    short* out   = isQ ? qout : kout;
    long ob      = isQ ? 4194304L : 1048576L;
    long oh      = isQ ? 256L : 524288L;
    long os      = isQ ? 2048L : 256L;
    float scale  = isQ ? 0.0625f : 1.0f;
    int vec = (isQ ? bid : bid - 8192) * 4 + (threadIdx.x >> 6);
    int lane = threadIdx.x & 63;
    int token = vec / H, head = vec % H;
    int b = token / S_LEN, s = token % S_LEN;

    bf16x4 xv = *(const bf16x4*)(C + (long)token * 3072 + cofs + head * 256 + lane * 4);
    float x0 = bf2f(xv[0]), x1 = bf2f(xv[1]), x2 = bf2f(xv[2]), x3 = bf2f(xv[3]);
    float ss = x0 * x0 + x1 * x1 + x2 * x2 + x3 * x3;
    #pragma unroll
    for (int m = 1; m < 64; m <<= 1) ss += __shfl_xor(ss, m);
    float inv = rsqrtf(ss * (1.f / 256.f) + 1e-6f);

    float4 wv = *(const float4*)(w + lane * 4);
    float y0 = x0 * inv * (1.f + wv.x);
    float y1 = x1 * inv * (1.f + wv.y);
    float y2 = x2 * inv * (1.f + wv.z);
    float y3 = x3 * inv * (1.f + wv.w);

    if (lane < 16) {
        float2 c = *(const float2*)&cosb[s * 32 + lane * 2];
        float2 sn = *(const float2*)&sinb[s * 32 + lane * 2];
        float a0 = y0 * c.x - y1 * sn.x, b0 = y0 * sn.x + y1 * c.x;
        float a1 = y2 * c.y - y3 * sn.y, b1 = y2 * sn.y + y3 * c.y;
        y0 = a0; y1 = b0; y2 = a1; y3 = b1;
    }
    y0 *= scale; y1 *= scale; y2 *= scale; y3 *= scale;
    long oidx = (long)b * ob + (long)head * oh + (long)s * os + lane * 4;
    bf16x4 o; o[0] = f2bf(y0); o[1] = f2bf(y1); o[2] = f2bf(y2); o[3] = f2bf(y3);
    *(bf16x4*)(out + oidx) = o;
}

// ---------------- V transpose: C[token][2560+kv*256+d] -> vr[b][kv][d][s] ---
__global__ __launch_bounds__(256) void transpose_v_kernel(const short* __restrict__ C,
                                                          short* __restrict__ vr) {
    __shared__ short tile[64][65];
    int s0 = blockIdx.x * 64, d0 = blockIdx.y * 64;
    int bkv = blockIdx.z; int b = bkv >> 1, kv = bkv & 1;
    int t = threadIdx.x;
    #pragma unroll
    for (int i = 0; i < 16; i++) {
        int flat = i * 256 + t; int si = flat >> 6, di = flat & 63;
        tile[si][di] = C[(long)(b * S_LEN + s0 + si) * 3072 + 2560 + kv * 256 + d0 + di];
    }
    __syncthreads();
    #pragma unroll
    for (int i = 0; i < 16; i++) {
        int flat = i * 256 + t; int di = flat >> 6, si = flat & 63;
        vr[(long)(bkv * 256 + d0 + di) * S_LEN + s0 + si] = tile[si][di];
    }
}

// ---------------- flash attention: byte-exact r8 (best measured, 112 us) ----
// 4 waves (2 q-groups x 2 key parities), 64 q rows/block, 2 blocks/CU.
// Phase: vmcnt(0)|BAR|compute|BAR|stage(ph+1). Heavy-first XCD mapping.
__global__ __launch_bounds__(256, 2) void flash_kernel(const short* __restrict__ Q,
                                                       const short* __restrict__ Kt,
                                                       const short* __restrict__ Vt,
                                                       short* __restrict__ O) {
    // [0,32K): K tiles (parity p at p*16KB); [32K,64K): V tiles; epilogue reuses
    __shared__ __align__(16) char smem[66048];

    int idx = blockIdx.x;
    int xcd = idx & 7, slot = idx >> 3;      // consecutive blocks -> XCD round-robin
    int bh = xcd * 2 + (slot & 1);           // 2 bh per XCD -> 4MB KV in its L2
    int j  = 31 - (slot >> 1);               // chunk 0..31, heavy first
    int h = bh & 7, b = bh >> 3;
    int kv = h >> 2;
    int t = threadIdx.x, lane = t & 63, w = t >> 6;
    int g = w >> 1, p = w & 1;               // q-group, key parity
    int ln = lane & 31, hi = lane >> 5;
    int q0 = j * 64 + g * 32;
    int qg = q0 + ln;                        // this lane's q row (score column)

    const short* Kb = Kt + (long)(b * NKV + kv) * S_LEN * HD;
    const short* Vb = Vt + (long)(b * NKV + kv) * HD * S_LEN;

    // Q fragments in registers: Q[q=ln][dc*16 + hi*8 + e]
    bf16x8 qf[16];
    {
        const short* qrow = Q + ((long)(b * S_LEN + qg) * NHQ + h) * HD + hi * 8;
        #pragma unroll
        for (int dc = 0; dc < 16; dc++) qf[dc] = *(const bf16x8*)&qrow[dc * 16];
    }

    f32x16 acc[8];
    #pragma unroll
    for (int i = 0; i < 8; i++)
        #pragma unroll
        for (int jj = 0; jj < 16; jj++) acc[i][jj] = 0.f;
    float m = -1e30f, l = 0.f;

    // stage tiles {2*ph2, 2*ph2+1} into parity slots 0/1 (16 loads/thread)
    auto stage = [&](int ph2) {
        #pragma unroll
        for (int pp = 0; pp < 2; pp++) {
            int k0s = (2 * ph2 + pp) * KVB;
            short* Ktile = (short*)(smem + pp * 16384);
            short* Vtile = (short*)(smem + 32768 + pp * 16384);
            #pragma unroll
            for (int c = 0; c < 4; c++) {
                int o = c * 4096 + w * 1024 + lane * 16;   // byte offset in tile
                int key = o >> 9, db = o & 511;
                gload16(Kb + (long)(k0s + key) * HD + ((db ^ ((key & 7) << 4)) >> 1),
                        Ktile + (c * 4096 + w * 1024) / 2);
                int d = o >> 6, kb = o & 63;
                gload16(Vb + (long)d * S_LEN + k0s + ((kb ^ ((d & 6) << 3)) >> 1),
                        Vtile + (c * 4096 + w * 1024) / 2);
            }
        }
    };

    auto compute = [&](int k0) {
        const char* Ks = (const char*)smem + p * 16384;
        const char* Vs = (const char*)smem + 32768 + p * 16384;
        // ---- QK^T (swapped): s = K * Q, D[key][q]; 2 chains ----
        f32x16 sA, sB;
        #pragma unroll
        for (int r = 0; r < 16; r++) { sA[r] = 0.f; sB[r] = 0.f; }
        __builtin_amdgcn_s_setprio(1);
        #pragma unroll
        for (int dc = 0; dc < 16; dc += 2) {
            int kb0 = (dc * 32 + hi * 16) ^ ((ln & 7) << 4);
            int kb1 = ((dc + 1) * 32 + hi * 16) ^ ((ln & 7) << 4);
            bf16x8 kf0 = *(const bf16x8*)(Ks + ln * 512 + kb0);
            bf16x8 kf1 = *(const bf16x8*)(Ks + ln * 512 + kb1);
            sA = __builtin_amdgcn_mfma_f32_32x32x16_bf16(kf0, qf[dc],     sA, 0, 0, 0);
            sB = __builtin_amdgcn_mfma_f32_32x32x16_bf16(kf1, qf[dc + 1], sB, 0, 0, 0);
        }
        __builtin_amdgcn_s_setprio(0);
        f32x16 s;
        #pragma unroll
        for (int r = 0; r < 16; r++) s[r] = sA[r] + sB[r];

        // ---- mask + online softmax, fully in-register ----
        if (k0 + KVB - 1 > q0) {
            #pragma unroll
            for (int r = 0; r < 16; r++) {
                int key_g = k0 + (r & 3) + 8 * (r >> 2) + 4 * hi;
                if (key_g > qg) s[r] = -1e30f;
            }
        }
        float mt = s[0];
        #pragma unroll
        for (int r = 1; r < 16; r++) mt = fmaxf(mt, s[r]);
        mt = fmaxf(mt, __shfl_xor(mt, 32));
        float mn = m;
        if (!__all(mt <= m + 8.f)) {           // defer-max (T13)
            mn = fmaxf(m, mt);
            float f = __expf(m - mn);
            m = mn;
            float fr[16];
            #pragma unroll
            for (int r = 0; r < 16; r++)
                fr[r] = bperm((r & 3) + 8 * (r >> 2) + 4 * hi, f);
            #pragma unroll
            for (int i = 0; i < 8; i++)
                #pragma unroll
                for (int r = 0; r < 16; r++) acc[i][r] *= fr[r];
            l *= f;
        }
        float pr[16], ps = 0.f;
        #pragma unroll
        for (int r = 0; r < 16; r++) { pr[r] = __expf(s[r] - mn); ps += pr[r]; }
        ps += __shfl_xor(ps, 32);
        l += ps;

        // ---- P -> bf16 A-fragments via cvt_pk + permlane32_swap (T12) ----
        unsigned pw[8];
        #pragma unroll
        for (int kc = 0; kc < 2; kc++) {
            unsigned X = cvtpk(pr[kc * 8 + 0], pr[kc * 8 + 1]);
            unsigned Y = cvtpk(pr[kc * 8 + 4], pr[kc * 8 + 5]);
            unsigned Z = cvtpk(pr[kc * 8 + 2], pr[kc * 8 + 3]);
            unsigned W = cvtpk(pr[kc * 8 + 6], pr[kc * 8 + 7]);
            asm volatile("v_permlane32_swap_b32 %0, %1" : "+v"(X), "+v"(Y));
            asm volatile("v_permlane32_swap_b32 %0, %1" : "+v"(Z), "+v"(W));
            pw[kc * 4 + 0] = X; pw[kc * 4 + 1] = Z;
            pw[kc * 4 + 2] = Y; pw[kc * 4 + 3] = W;
        }
        u32x4 w0v = {pw[0], pw[1], pw[2], pw[3]};
        u32x4 w1v = {pw[4], pw[5], pw[6], pw[7]};
        bf16x8 pa0 = __builtin_bit_cast(bf16x8, w0v);
        bf16x8 pa1 = __builtin_bit_cast(bf16x8, w1v);

        // ---- PV: acc[db] += P * V, D[q][d], lane owns d column ----
        __builtin_amdgcn_s_setprio(1);
        #pragma unroll
        for (int db = 0; db < 8; db++) {
            int drow = db * 32 + ln;
            int sw = (drow & 6) << 3;
            bf16x8 vf0 = *(const bf16x8*)(Vs + drow * 64 + ((hi * 16) ^ sw));
            bf16x8 vf1 = *(const bf16x8*)(Vs + drow * 64 + ((32 + hi * 16) ^ sw));
            acc[db] = __builtin_amdgcn_mfma_f32_32x32x16_bf16(pa0, vf0, acc[db], 0, 0, 0);
            acc[db] = __builtin_amdgcn_mfma_f32_32x32x16_bf16(pa1, vf1, acc[db], 0, 0, 0);
        }
        __builtin_amdgcn_s_setprio(0);
    };

    stage(0);
    for (int ph = 0; ph <= j; ph++) {
        asm volatile("s_waitcnt vmcnt(0)" ::: "memory");
        __builtin_amdgcn_s_barrier();
        int k0 = (2 * ph + p) * KVB;
        if (k0 <= q0 + 31) compute(k0);      // skip only fully-masked diagonal tile
        __builtin_amdgcn_s_barrier();
        if (ph < j) stage(ph + 1);
        __builtin_amdgcn_sched_barrier(0);
    }

    // ---- parity merge epilogue (staging LDS is dead) ----
    float* accb = (float*)smem;                 // [g][128][64] f32
    float* mlb  = (float*)(smem + 65536);       // m: [0,64), l: [64,128)
    if (p == 1) {
        #pragma unroll
        for (int db = 0; db < 8; db++)
            #pragma unroll
            for (int r = 0; r < 16; r++)
                accb[g * 8192 + (db * 16 + r) * 64 + hi * 32 + ln] = acc[db][r];
        if (hi == 0) { mlb[g * 32 + ln] = m; mlb[64 + g * 32 + ln] = l; }
    }
    __syncthreads();
    if (p == 0) {
        float m1 = mlb[g * 32 + ln], l1 = mlb[64 + g * 32 + ln];
        float M  = fmaxf(m, m1);
        float f0 = __expf(m - M), f1 = __expf(m1 - M);
        float lt = l * f0 + l1 * f1;
        float w0 = f0 / lt, w1 = f1 / lt;
        float fr0[16], fr1[16];
        #pragma unroll
        for (int r = 0; r < 16; r++) {
            int crow = (r & 3) + 8 * (r >> 2) + 4 * hi;
            fr0[r] = bperm(crow, w0);
            fr1[r] = bperm(crow, w1);
        }
        #pragma unroll
        for (int db = 0; db < 8; db++)
            #pragma unroll
            for (int r = 0; r < 16; r++) {
                float a1 = accb[g * 8192 + (db * 16 + r) * 64 + hi * 32 + ln];
                int qrow = q0 + (r & 3) + 8 * (r >> 2) + 4 * hi;
                O[(long)(b * S_LEN + qrow) * 2048 + h * HD + db * 32 + ln] =
                    f2bf(acc[db][r] * fr0[r] + a1 * fr1[r]);
            }
    }
}

extern "C" void kernel_launch(void* const* d_in, const int* in_sizes, int n_in,
                              void* d_out, int out_size, void* d_ws, size_t ws_size,
                              hipStream_t stream) {
    const float* x    = (const float*)d_in[0];
    const float* cosb = (const float*)d_in[1];
    const float* sinb = (const float*)d_in[2];
    // d_in[3] = mask: equivalent to causal; computed analytically in-kernel
    const float* wq   = (const float*)d_in[4];
    const float* wk   = (const float*)d_in[5];
    const float* wv   = (const float*)d_in[6];
    const float* wo   = (const float*)d_in[7];
    const float* qnw  = (const float*)d_in[8];
    const float* knw  = (const float*)d_in[9];
    float* out = (float*)d_out;

    char* ws = (char*)d_ws;
    short* xb   = (short*)(ws + 0);          // 4096x512 bf16               [0, 4194304)
    short* wfus = (short*)(ws + 4194304);    // [3072][512] wq|wk|wv^T      [4194304, 7340032)
    short* wot  = (short*)(ws + 7340032);    // [512][2048] wo^T            [7340032, 9437184)
    short* C    = (short*)(ws + 9437184);    // 4096x3072 fused QKV out     [9437184, 34603008)
    short* ao   = (short*)(ws + 9437184);    // flash out aliases C (C dead by then)
    short* qro  = (short*)(ws + 34603008);   // 4096x2048 roped Q           [34603008, 51380224)
    short* kr   = (short*)(ws + 51380224);   // [b][kv][s][d] 4 MB          [51380224, 55574528)
    short* vr   = (short*)(ws + 55574528);   // [b][kv][d][s] 4 MB          [55574528, 59768832)

    cvt_kernel<<<2048, 256, 0, stream>>>(x, xb, 2097152);
    wt_all_kernel<<<640, 256, 0, stream>>>(wq, wk, wv, wo, wfus, wot);

    // fused QKV projection: C[4096][3072]
    gemm_bt<128, 1><<<dim3(24, 32), 256, 0, stream>>>(xb, wfus, C, 4096, 3072, 512);

    // Q (scale 1/16 folded) + K norm/rope in one launch
    norm_rope2_kernel<<<10240, 256, 0, stream>>>(C, qro, kr, qnw, knw, cosb, sinb);
    transpose_v_kernel<<<dim3(32, 4, 4), 256, 0, stream>>>(C, vr);

    flash_kernel<<<512, 256, 0, stream>>>(qro, kr, vr, ao);

    gemm_bt<64, 0><<<dim3(8, 32), 256, 0, stream>>>(ao, wot, out, 4096, 512, 2048);
}